// Round 16
// baseline (388.070 us; speedup 1.0000x reference)
//
#include <hip/hip_runtime.h>
#include <math.h>

#define NB 4
#define SEQ 8192
#define NT (NB*SEQ)        // 32768 tokens
#define HDIM 64
#define NST 16
#define NBLK 4
#define KCONV 16
#define DIN 128
#define PDIM 16            // head dim
#define NH 8
#define CDIM 160
#define EPROJ 296
#define CH 128             // chunk length
#define NC 64              // chunks per sequence

typedef __attribute__((ext_vector_type(8))) short short8;
typedef __attribute__((ext_vector_type(4))) float f32x4;

__device__ __forceinline__ float sigf(float x){ return 1.0f/(1.0f+__expf(-x)); }

__device__ __forceinline__ unsigned short bf16r(float f){
  unsigned int u = __float_as_uint(f);
  u = (u + 0x7fffu + ((u >> 16) & 1u)) >> 16;
  return (unsigned short)u;
}
__device__ __forceinline__ unsigned int pk_bf16(float a, float b){
  return (unsigned int)bf16r(a) | ((unsigned int)bf16r(b) << 16);
}
__device__ __forceinline__ float bf16f(unsigned short h){
  return __uint_as_float(((unsigned int)h) << 16);
}

// h[t][d] = x[t] * w_in[d]
__global__ __launch_bounds__(256) void k_init_h(const float* __restrict__ x, const float* __restrict__ w_in,
                                                float* __restrict__ h){
  int i = blockIdx.x*256 + threadIdx.x;
  int t = i >> 6, d = i & 63;
  h[i] = x[t]*w_in[d];
}

// split all 4 layers' in_proj weights into bf16 hi/lo pair (once per call)
__global__ __launch_bounds__(256) void k_wsplit(const float* __restrict__ w,
                                                unsigned short* __restrict__ whi,
                                                unsigned short* __restrict__ wlo){
  int i = blockIdx.x*256 + threadIdx.x;
  if(i < NBLK*EPROJ*HDIM){
    float f = w[i];
    unsigned short hi = bf16r(f);
    float fh = bf16f(hi);
    whi[i] = hi;
    wlo[i] = bf16r(f - fh);
  }
}

// in-proj via split-bf16 MFMA. Outputs split by consumer precision:
//   e in [0,128)    -> zxz  bf16 (z gate; consumer rounds to bf16 anyway)
//   e in [128,288)  -> zxcb bf16 (conv inputs; conv output is bf16-rounded anyway)
//   e in [288,296)  -> zxd  fp32 (raw dt: softplus->cumsum->exp chain, precision-critical)
__global__ __launch_bounds__(256) void k_inproj(const float* __restrict__ h,
                                                const unsigned short* __restrict__ whi,
                                                const unsigned short* __restrict__ wlo,
                                                unsigned short* __restrict__ zxz,
                                                unsigned short* __restrict__ zxcb,
                                                float* __restrict__ zxd){
  int tid = threadIdx.x;
  int lane = tid & 63, wid = tid >> 6;
  int quad = lane >> 4, lq = lane & 15;
  int t0 = blockIdx.x*64 + wid*16;

  const float* hp = h + (size_t)(t0+lq)*HDIM;
  short8 bh[2], bl[2];
#pragma unroll
  for(int kb=0;kb<2;kb++){
    float4 f0 = *(const float4*)(hp + kb*32 + quad*8);
    float4 f1 = *(const float4*)(hp + kb*32 + quad*8 + 4);
    float v[8] = {f0.x,f0.y,f0.z,f0.w,f1.x,f1.y,f1.z,f1.w};
#pragma unroll
    for(int j=0;j<8;j++){
      unsigned short hi = bf16r(v[j]);
      bh[kb][j] = (short)hi;
      bl[kb][j] = (short)bf16r(v[j] - bf16f(hi));
    }
  }

  for(int et=0; et<19; et++){
    int e_a = et*16 + lq;
    int ec = (e_a < EPROJ) ? e_a : (EPROJ-1);
    const unsigned short* wh = whi + (size_t)ec*HDIM + quad*8;
    const unsigned short* wl = wlo + (size_t)ec*HDIM + quad*8;
    short8 ah0 = *(const short8*)wh;
    short8 ah1 = *(const short8*)(wh + 32);
    short8 al0 = *(const short8*)wl;
    short8 al1 = *(const short8*)(wl + 32);
    f32x4 acc = {0.f,0.f,0.f,0.f};
    acc = __builtin_amdgcn_mfma_f32_16x16x32_bf16(ah0, bh[0], acc, 0, 0, 0);
    acc = __builtin_amdgcn_mfma_f32_16x16x32_bf16(ah1, bh[1], acc, 0, 0, 0);
    acc = __builtin_amdgcn_mfma_f32_16x16x32_bf16(ah0, bl[0], acc, 0, 0, 0);
    acc = __builtin_amdgcn_mfma_f32_16x16x32_bf16(ah1, bl[1], acc, 0, 0, 0);
    acc = __builtin_amdgcn_mfma_f32_16x16x32_bf16(al0, bh[0], acc, 0, 0, 0);
    acc = __builtin_amdgcn_mfma_f32_16x16x32_bf16(al1, bh[1], acc, 0, 0, 0);
#pragma unroll
    for(int r=0;r<4;r++){
      int e = et*16 + quad*4 + r;
      if(e < 128)        zxz[(size_t)e*NT + t0 + lq] = bf16r(acc[r]);
      else if(e < 288)   zxcb[(size_t)(e-128)*NT + t0 + lq] = bf16r(acc[r]);
      else if(e < EPROJ) zxd[(size_t)(e-288)*NT + t0 + lq] = acc[r];
    }
  }
}

// Fused mid-section per (b,chunk): conv+silu -> xbc bf16 (+LDS hi/lo), dt softplus,
// per-head cumsum, chunk-states via split-bf16 MFMA. Conv inputs bf16 (3 uint4 loads/group).
__global__ __launch_bounds__(512) void k_mid(const unsigned short* __restrict__ zxcb,
                                             const float* __restrict__ zxd,
                                             const float* __restrict__ cw, const float* __restrict__ cb,
                                             const float* __restrict__ dtb, const float* __restrict__ alog,
                                             unsigned short* __restrict__ xbc, float* __restrict__ dt,
                                             float* __restrict__ acs, float* __restrict__ asum,
                                             float* __restrict__ S){
  __shared__ unsigned short XhT[128][136];
  __shared__ unsigned short XlT[128][136];
  __shared__ unsigned short BhT[16][136];
  __shared__ unsigned short BlT[16][136];
  __shared__ float dtl[8][128];
  __shared__ float wle[8][128];

  int bc = blockIdx.x;
  int c = bc & 63, b = bc >> 6;
  int t0 = b*SEQ + c*CH;
  int tid = threadIdx.x;

  // ---- conv + silu: 5 groups of 8 outputs per thread (bf16 input window) ----
  for(int it=0; it<5; it++){
    int G = tid + it*512;            // 0..2559 (160 ch x 16 groups)
    int ch = G >> 4;
    int sg = (G & 15) * 8;
    const unsigned short* p = zxcb + (size_t)ch*NT + t0 + sg - 16;
    float buf[24];
    if(c == 0 && sg < 16){
#pragma unroll
      for(int j=0;j<24;j++){
        int l = sg - 16 + j;
        buf[j] = (l >= 0) ? bf16f(p[j]) : 0.f;
      }
    } else {
#pragma unroll
      for(int q=0;q<3;q++){
        uint4 u = *(const uint4*)(p + q*8);
        buf[q*8+0]=bf16f((unsigned short)(u.x&0xffffu)); buf[q*8+1]=bf16f((unsigned short)(u.x>>16));
        buf[q*8+2]=bf16f((unsigned short)(u.y&0xffffu)); buf[q*8+3]=bf16f((unsigned short)(u.y>>16));
        buf[q*8+4]=bf16f((unsigned short)(u.z&0xffffu)); buf[q*8+5]=bf16f((unsigned short)(u.z>>16));
        buf[q*8+6]=bf16f((unsigned short)(u.w&0xffffu)); buf[q*8+7]=bf16f((unsigned short)(u.w>>16));
      }
    }
    float wv[16];
#pragma unroll
    for(int k=0;k<16;k++) wv[k] = cw[ch*KCONV+k];
    float bias = cb[ch];
    unsigned short hs[8];
#pragma unroll
    for(int s=0;s<8;s++){
      float acc = bias;
#pragma unroll
      for(int k=0;k<16;k++) acc += wv[k]*buf[s+1+k];
      float r = acc * sigf(acc);
      unsigned short hi = bf16r(r);
      unsigned short lo = bf16r(r - bf16f(hi));
      hs[s] = hi;
      if(ch < 128){ XhT[ch][sg+s] = hi; XlT[ch][sg+s] = lo; }
      else if(ch < 144){ BhT[ch-128][sg+s] = hi; BlT[ch-128][sg+s] = lo; }
    }
    uint4 pk;
    pk.x = (unsigned int)hs[0] | ((unsigned int)hs[1] << 16);
    pk.y = (unsigned int)hs[2] | ((unsigned int)hs[3] << 16);
    pk.z = (unsigned int)hs[4] | ((unsigned int)hs[5] << 16);
    pk.w = (unsigned int)hs[6] | ((unsigned int)hs[7] << 16);
    *(uint4*)(xbc + (size_t)ch*NT + t0 + sg) = pk;
  }
  // ---- dt softplus (fp32 raw dt) ----
#pragma unroll
  for(int k=0;k<2;k++){
    int idx = tid + k*512;
    int hh = idx >> 7, s = idx & 127;
    float raw = zxd[(size_t)hh*NT + t0 + s] + dtb[hh];
    float v = (raw > 20.f) ? raw : log1pf(__expf(raw));
    dtl[hh][s] = v;
    dt[(size_t)hh*NT + t0 + s] = v;
  }
  __syncthreads();

  int lane = tid & 63, wid = tid >> 6;
  {
    int hh = wid;
    float A = -__expf(alog[hh]);
    float d0 = dtl[hh][2*lane], d1 = dtl[hh][2*lane+1];
    float v0 = d0*A, v1 = d1*A;
    float s = v0 + v1;
    for(int off=1; off<64; off<<=1){
      float o = __shfl_up(s, off);
      if(lane >= off) s += o;
    }
    float tot = __shfl(s, 63);
    float excl = s - (v0+v1);
    float a0 = excl+v0, a1 = excl+v0+v1;
    *(float2*)&acs[(size_t)hh*NT + t0 + 2*lane] = make_float2(a0, a1);
    if(lane == 63) asum[(size_t)bc*NH + hh] = tot;
    wle[hh][2*lane]   = d0*__expf(tot - a0);
    wle[hh][2*lane+1] = d1*__expf(tot - a1);
  }
  __syncthreads();

  {
    int hh = wid;
    int lq = lane & 15, quad = lane >> 4;
    f32x4 acc = {0.f,0.f,0.f,0.f};
#pragma unroll
    for(int kb=0;kb<4;kb++){
      int k0 = kb*32 + quad*8;
      short8 xh = *(const short8*)&XhT[hh*16 + lq][k0];
      short8 xl = *(const short8*)&XlT[hh*16 + lq][k0];
      short8 ah, al;
#pragma unroll
      for(int j=0;j<8;j++){
        float xv = bf16f((unsigned short)xh[j]) + bf16f((unsigned short)xl[j]);
        float pw = xv * wle[hh][k0 + j];
        unsigned short hi = bf16r(pw);
        ah[j] = (short)hi;
        al[j] = (short)bf16r(pw - bf16f(hi));
      }
      short8 bh = *(const short8*)&BhT[lq][k0];
      short8 bl = *(const short8*)&BlT[lq][k0];
      acc = __builtin_amdgcn_mfma_f32_16x16x32_bf16(ah, bh, acc, 0, 0, 0);
      acc = __builtin_amdgcn_mfma_f32_16x16x32_bf16(ah, bl, acc, 0, 0, 0);
      acc = __builtin_amdgcn_mfma_f32_16x16x32_bf16(al, bh, acc, 0, 0, 0);
    }
    float* Sp = S + ((size_t)bc*NH + hh)*256;
#pragma unroll
    for(int r=0;r<4;r++) Sp[(quad*4 + r)*16 + lq] = acc[r];
  }
}

// sequential inter-chunk scan; 4-deep rolling prefetch.
__global__ __launch_bounds__(64) void k_scan(const float* __restrict__ S, const float* __restrict__ asum,
                                             const float* __restrict__ init, float* __restrict__ prev){
  int q  = blockIdx.x & 3;
  int hh = (blockIdx.x >> 2) & 7;
  int b  = blockIdx.x >> 5;
  int el = q*64 + threadIdx.x;
  const size_t cs = (size_t)NH*256;
  const float* Sp = S + ((size_t)(b*NC)*NH + hh)*256 + el;
  float* Pp = prev + ((size_t)(b*NC)*NH + hh)*256 + el;
  const float* ap = asum + (size_t)(b*NC)*NH + hh;
  float r = init[hh*256 + el];
  float s0 = Sp[0], s1 = Sp[cs], s2 = Sp[2*cs], s3 = Sp[3*cs];
  for(int c=0;c<NC;c+=4){
    Pp[(size_t)c*cs] = r;
    r = __expf(ap[(size_t)c*NH])*r + s0;
    s0 = (c+4 < NC) ? Sp[(size_t)(c+4)*cs] : 0.f;
    Pp[(size_t)(c+1)*cs] = r;
    r = __expf(ap[(size_t)(c+1)*NH])*r + s1;
    s1 = (c+5 < NC) ? Sp[(size_t)(c+5)*cs] : 0.f;
    Pp[(size_t)(c+2)*cs] = r;
    r = __expf(ap[(size_t)(c+2)*NH])*r + s2;
    s2 = (c+6 < NC) ? Sp[(size_t)(c+6)*cs] : 0.f;
    Pp[(size_t)(c+3)*cs] = r;
    r = __expf(ap[(size_t)(c+3)*NH])*r + s3;
    s3 = (c+7 < NC) ? Sp[(size_t)(c+7)*cs] : 0.f;
  }
}

// Fused tail per (b,chunk). Barrier-minimized (3 cross-wave crossings).
__global__ __launch_bounds__(512) void k_tail(const unsigned short* __restrict__ xbc,
                                              const unsigned short* __restrict__ zxz,
                                              const float* __restrict__ dt, const float* __restrict__ acs,
                                              const float* __restrict__ prev, const float* __restrict__ dskip,
                                              const float* __restrict__ nw, const float* __restrict__ opw,
                                              const float* __restrict__ mw, const float* __restrict__ mb,
                                              float* __restrict__ h){
  __shared__ __align__(16) unsigned char sm[142336];
  unsigned short* Bb   = (unsigned short*)(sm);             // [128][24]
  unsigned short* Cb   = (unsigned short*)(sm + 6144);      // [128][24]
  unsigned short* XbT  = (unsigned short*)(sm + 12288);     // [128][168]
  unsigned short* Sraw = (unsigned short*)(sm + 55296);     // [128][136]
  unsigned short* P    = (unsigned short*)(sm + 90112);     // [128][168]
  float* Al  = (float*)(sm + 133120);                       // [8][128]
  float* Dtl = (float*)(sm + 137216);                       // [8][128]
  float* nwl = (float*)(sm + 141312);                       // 128
  float* mbl = (float*)(sm + 141824);                       // 64
  unsigned short* zbuf = (unsigned short*)(sm + 142080);    // 16
  unsigned short* Wo = Sraw;                                // [64][136]
  unsigned short* Wm = Sraw + 64*136;                       // [64][72]
  unsigned short* Zb = XbT;                                 // [128][136]
  unsigned short* Yn = P;                                   // [128][136]
  unsigned short* Tt = P;                                   // [128][136] cols 0..63

  int bc = blockIdx.x;
  int c = bc & 63, b = bc >> 6;
  int t0 = b*SEQ + c*CH;
  int tid = threadIdx.x, lane = tid & 63, wid = tid >> 6;
  int quad = lane >> 4, lq = lane & 15;

  // ---- staging ----
#pragma unroll
  for(int k=0;k<8;k++){                 // B/C: 32ch x 128 (bf16 passthrough)
    int idx = tid + k*512;
    int ch = idx >> 7, s = idx & 127;
    unsigned short f = xbc[(size_t)(DIN+ch)*NT + t0 + s];
    if(ch < 16) Bb[s*24 + ch] = f;
    else        Cb[s*24 + ch-16] = f;
  }
#pragma unroll
  for(int k=0;k<8;k++){                 // X*dt: 128 x 128
    int fi = tid + k*512;
    int p = fi >> 5, s4 = fi & 31;
    uint2 xu = *(const uint2*)&xbc[(size_t)p*NT + t0 + s4*4];
    float4 dv = *(const float4*)&dt[(size_t)(p>>4)*NT + t0 + s4*4];
    float x0 = bf16f((unsigned short)(xu.x & 0xffffu));
    float x1 = bf16f((unsigned short)(xu.x >> 16));
    float x2 = bf16f((unsigned short)(xu.y & 0xffffu));
    float x3 = bf16f((unsigned short)(xu.y >> 16));
    *(unsigned int*)&XbT[p*168 + s4*4]   = pk_bf16(x0*dv.x, x1*dv.y);
    *(unsigned int*)&XbT[p*168 + s4*4+2] = pk_bf16(x2*dv.z, x3*dv.w);
  }
#pragma unroll
  for(int k=0;k<4;k++){                 // prev ext
    int idx = tid + k*512;
    int hh = idx >> 8, rest = idx & 255;
    int p = rest >> 4, n = rest & 15;
    XbT[(hh*16+p)*168 + 128 + n] = bf16r(prev[((size_t)bc*NH + hh)*256 + rest]);
  }
#pragma unroll
  for(int k=0;k<3;k++){                 // XbT pad 144..167
    int idx = tid + k*512;
    int p = idx / 12, cc = idx - p*12;
    *(unsigned int*)&XbT[p*168 + 144 + 2*cc] = 0u;
  }
#pragma unroll
  for(int k=0;k<2;k++){                 // Al / Dtl
    int idx = tid + k*512;
    int hh = idx >> 7, s = idx & 127;
    Al[hh*128+s]  = acs[(size_t)hh*NT + t0 + s];
    Dtl[hh*128+s] = dt[(size_t)hh*NT + t0 + s];
  }
  if(tid < 128) nwl[tid] = nw[tid];
  else if(tid < 192) mbl[tid-128] = mb[tid-128];
  else if(tid < 208) zbuf[tid-192] = 0;
  __syncthreads();                      // (1) staging visible to all waves

  // ---- score: S = C.B^T once, 16-row strip per wave (strip-private below) ----
  int strip = wid*16;
  short8 afr;
  {
    int row = strip + lq;
    const unsigned short* ap = (quad < 2) ? &Cb[row*24 + quad*8] : zbuf;
    afr = *(const short8*)ap;
  }
  for(int nt=0;nt<8;nt++){
    const unsigned short* bp = (quad < 2) ? &Bb[(nt*16+lq)*24 + quad*8] : zbuf;
    short8 bfr = *(const short8*)bp;
    f32x4 acc = {0.f,0.f,0.f,0.f};
    acc = __builtin_amdgcn_mfma_f32_16x16x32_bf16(afr, bfr, acc, 0, 0, 0);
#pragma unroll
    for(int r=0;r<4;r++)
      Sraw[(strip+quad*4+r)*136 + nt*16+lq] = bf16r(acc[r]);
  }
  // no barrier: Sraw rows strip-private

  // ---- per-head: P build + PV + D-skip (P rows strip-private) ----
  f32x4 accv[8];
  int c0 = 2*lane, c1 = 2*lane+1;
  for(int hh2=0; hh2<8; hh2++){
    const float* Alh = Al + hh2*128;
    const float* Dth = Dtl + hh2*128;
    float as0 = Alh[c0], as1 = Alh[c1];
#pragma unroll
    for(int rr=0;rr<16;rr++){
      int row = strip + rr;
      float alr = Alh[row];
      unsigned int sv = *(unsigned int*)&Sraw[row*136 + c0];
      float s0 = bf16f((unsigned short)(sv & 0xffffu));
      float s1 = bf16f((unsigned short)(sv >> 16));
      float p0 = s0 * __expf(alr - as0);     // dt NOT applied: already in XbT (x*dt)
      float p1 = s1 * __expf(alr - as1);
      p0 = (c0 <= row) ? p0 : 0.f;
      p1 = (c1 <= row) ? p1 : 0.f;
      *(unsigned int*)&P[row*168 + c0] = pk_bf16(p0, p1);
    }
    {   // ext cols 128..143: C[row][n]*exp(Al[row])
      int n = lane & 15, rg = lane >> 4;
#pragma unroll
      for(int rr=0;rr<4;rr++){
        int row = strip + rg*4 + rr;
        float ea = __expf(Alh[row]);
        P[row*168 + 128 + n] = bf16r(bf16f(Cb[row*24+n]) * ea);
      }
    }
    {   // pad cols 144..159 = 0
      int cc = lane & 7, rg = lane >> 3;
#pragma unroll
      for(int rr=0;rr<2;rr++){
        int row = strip + rg*2 + rr;
        *(unsigned int*)&P[row*168 + 144 + 2*cc] = 0u;
      }
    }
    f32x4 acc2 = {0.f,0.f,0.f,0.f};
#pragma unroll
    for(int ks=0;ks<5;ks++){
      short8 bfr = *(const short8*)&XbT[(hh2*16+lq)*168 + ks*32 + quad*8];
      short8 af  = *(const short8*)&P[(strip+lq)*168 + ks*32 + quad*8];
      acc2 = __builtin_amdgcn_mfma_f32_16x16x32_bf16(af, bfr, acc2, 0, 0, 0);
    }
    float Dk = dskip[hh2];
#pragma unroll
    for(int r=0;r<4;r++){
      int l = strip + quad*4 + r;
      float xdt = bf16f(XbT[(hh2*16+lq)*168 + l]);
      float dtv = fmaxf(Dth[l], 1e-30f);
      acc2[r] += Dk * xdt * __frcp_rn(dtv);
    }
    accv[hh2] = acc2;
  }
  __syncthreads();   // (2) WAR: all waves done reading XbT/Sraw before overwrite

  // ---- stage z (bf16 passthrough into XbT region), Wo/Wm (into Sraw region) ----
#pragma unroll
  for(int k=0;k<8;k++){
    int fi = tid + k*512;
    int p = fi >> 5, s4 = fi & 31;
    uint2 zu = *(const uint2*)&zxz[(size_t)p*NT + t0 + s4*4];
    *(unsigned int*)&Zb[p*136 + s4*4]   = zu.x;
    *(unsigned int*)&Zb[p*136 + s4*4+2] = zu.y;
  }
#pragma unroll
  for(int k=0;k<4;k++){
    int fi = tid + k*512;
    int n = fi >> 5, k4 = fi & 31;
    float4 wv = *(const float4*)&opw[(size_t)n*DIN + k4*4];
    *(unsigned int*)&Wo[n*136 + k4*4]   = pk_bf16(wv.x, wv.y);
    *(unsigned int*)&Wo[n*136 + k4*4+2] = pk_bf16(wv.z, wv.w);
  }
#pragma unroll
  for(int k=0;k<2;k++){
    int fi = tid + k*512;
    int n = fi >> 4, k4 = fi & 15;
    float4 wv = *(const float4*)&mw[(size_t)n*HDIM + k4*4];
    *(unsigned int*)&Wm[n*72 + k4*4]   = pk_bf16(wv.x, wv.y);
    *(unsigned int*)&Wm[n*72 + k4*4+2] = pk_bf16(wv.z, wv.w);
  }
  __syncthreads();   // (3) Zb/Wo/Wm visible (read cross-strip below)

  // ---- gate by silu(z), RMS (shfl over lq), write y_norm bf16 ----
  float rms_[4];
#pragma unroll
  for(int r=0;r<4;r++){
    int l = strip + quad*4 + r;
    float part = 0.f;
#pragma unroll
    for(int hh2=0;hh2<8;hh2++){
      float zv = bf16f(Zb[(hh2*16+lq)*136 + l]);
      float g = zv * sigf(zv);
      float yv = accv[hh2][r] * g;
      accv[hh2][r] = yv;
      part += yv*yv;
    }
    part += __shfl_xor(part,1); part += __shfl_xor(part,2);
    part += __shfl_xor(part,4); part += __shfl_xor(part,8);
    rms_[r] = rsqrtf(part*(1.0f/128.0f) + 1e-5f);
  }
#pragma unroll
  for(int hh2=0;hh2<8;hh2++){
    float nwv = nwl[hh2*16+lq];
#pragma unroll
    for(int r=0;r<4;r++){
      int l = strip + quad*4 + r;
      Yn[l*136 + hh2*16+lq] = bf16r(accv[hh2][r]*rms_[r]*nwv);
    }
  }
  // no barrier: Yn rows strip-private

  // ---- out_proj: (128 x 64) = Yn (K=128) x Wo ----
  short8 afk[4];
#pragma unroll
  for(int ks=0;ks<4;ks++) afk[ks] = *(const short8*)&Yn[(strip+lq)*136 + ks*32 + quad*8];
  f32x4 aco[4];
#pragma unroll
  for(int nt=0;nt<4;nt++){ aco[nt] = (f32x4){0.f,0.f,0.f,0.f}; }
#pragma unroll
  for(int nt=0;nt<4;nt++){
#pragma unroll
    for(int ks=0;ks<4;ks++){
      short8 bfr = *(const short8*)&Wo[(nt*16+lq)*136 + ks*32 + quad*8];
      aco[nt] = __builtin_amdgcn_mfma_f32_16x16x32_bf16(afk[ks], bfr, aco[nt], 0, 0, 0);
    }
  }

  // softsign -> Tt
#pragma unroll
  for(int nt=0;nt<4;nt++){
#pragma unroll
    for(int r=0;r<4;r++){
      int l = strip + quad*4 + r;
      float o = aco[nt][r];
      Tt[l*136 + nt*16+lq] = bf16r(o * rsqrtf(1.0f + o*o));
    }
  }
  // no barrier: Tt rows strip-private

  // ---- mlp: (128 x 64) = Tt (K=64) x Wm ----
  f32x4 acm[4];
#pragma unroll
  for(int nt=0;nt<4;nt++){ acm[nt] = (f32x4){0.f,0.f,0.f,0.f}; }
#pragma unroll
  for(int ks=0;ks<2;ks++){
    short8 af = *(const short8*)&Tt[(strip+lq)*136 + ks*32 + quad*8];
#pragma unroll
    for(int nt=0;nt<4;nt++){
      short8 bfr = *(const short8*)&Wm[(nt*16+lq)*72 + ks*32 + quad*8];
      acm[nt] = __builtin_amdgcn_mfma_f32_16x16x32_bf16(af, bfr, acm[nt], 0, 0, 0);
    }
  }
  // ---- residual h += mlp + bias ----
#pragma unroll
  for(int nt=0;nt<4;nt++){
#pragma unroll
    for(int r=0;r<4;r++){
      int l = strip + quad*4 + r;
      int d = nt*16 + lq;
      size_t gi = (size_t)(t0+l)*HDIM + d;
      h[gi] += acm[nt][r] + mbl[d];
    }
  }
}

__global__ __launch_bounds__(256) void k_final(const float* __restrict__ h, const float* __restrict__ wout,
                                               float* __restrict__ out){
  int t = blockIdx.x*256 + threadIdx.x;
  const float4* hp = (const float4*)(h + (size_t)t*HDIM);
  float acc = 0.f;
#pragma unroll
  for(int i=0;i<16;i++){
    float4 hv = hp[i]; float4 wv = ((const float4*)wout)[i];
    acc += hv.x*wv.x + hv.y*wv.y + hv.z*wv.z + hv.w*wv.w;
  }
  out[t] = acc;
}

extern "C" void kernel_launch(void* const* d_in, const int* in_sizes, int n_in,
                              void* d_out, int out_size, void* d_ws, size_t ws_size,
                              hipStream_t stream){
  const float* x          = (const float*)d_in[0];
  const float* w_in       = (const float*)d_in[1];
  const float* w_out      = (const float*)d_in[2];
  const float* in_proj_w  = (const float*)d_in[3];
  const float* conv_w     = (const float*)d_in[4];
  const float* conv_b     = (const float*)d_in[5];
  const float* dt_bias    = (const float*)d_in[6];
  const float* A_log      = (const float*)d_in[7];
  const float* D_skip     = (const float*)d_in[8];
  const float* init_st    = (const float*)d_in[9];
  const float* norm_w     = (const float*)d_in[10];
  const float* out_proj_w = (const float*)d_in[11];
  const float* mlp_w      = (const float*)d_in[12];
  const float* mlp_b      = (const float*)d_in[13];
  float* out = (float*)d_out;

  float* ws = (float*)d_ws;
  float* h    = ws; ws += (size_t)NT*HDIM;
  unsigned short* zxz  = (unsigned short*)ws; ws += (size_t)(128*NT)/2;   // bf16 z
  unsigned short* zxcb = (unsigned short*)ws; ws += (size_t)(CDIM*NT)/2;  // bf16 conv-in
  float* zxd  = ws; ws += (size_t)NH*NT;                                  // fp32 raw dt
  unsigned short* xbc = (unsigned short*)ws; ws += (size_t)(CDIM*NT)/2;   // bf16 conv out
  float* dt   = ws; ws += (size_t)NH*NT;
  float* acs  = ws; ws += (size_t)NH*NT;
  float* asum = ws; ws += (size_t)NB*NC*NH;
  float* S    = ws; ws += (size_t)NB*NC*NH*256;
  float* prev = ws; ws += (size_t)NB*NC*NH*256;
  unsigned short* whi = (unsigned short*)ws; ws += (size_t)(NBLK*EPROJ*HDIM)/2;
  unsigned short* wlo = (unsigned short*)ws; ws += (size_t)(NBLK*EPROJ*HDIM)/2;

  k_init_h<<<(NT*HDIM)/256, 256, 0, stream>>>(x, w_in, h);
  k_wsplit<<<(NBLK*EPROJ*HDIM + 255)/256, 256, 0, stream>>>(in_proj_w, whi, wlo);
  for(int i=0;i<NBLK;i++){
    k_inproj<<<NT/64, 256, 0, stream>>>(h, whi + (size_t)i*EPROJ*HDIM,
                                        wlo + (size_t)i*EPROJ*HDIM, zxz, zxcb, zxd);
    k_mid   <<<NB*NC, 512, 0, stream>>>(zxcb, zxd, conv_w + i*CDIM*KCONV, conv_b + i*CDIM,
                                        dt_bias + i*NH, A_log + i*NH,
                                        xbc, dt, acs, asum, S);
    k_scan  <<<NB*NH*4, 64, 0, stream>>>(S, asum, init_st + i*NH*256, prev);
    k_tail  <<<NB*NC, 512, 0, stream>>>(xbc, zxz, dt, acs, prev, D_skip + i*NH,
                                        norm_w + i*DIN, out_proj_w + i*HDIM*DIN,
                                        mlp_w + i*HDIM*HDIM, mlp_b + i*HDIM, h);
  }
  k_final<<<NT/256, 256, 0, stream>>>(h, w_out, out);
}

// Round 17
// 379.288 us; speedup vs baseline: 1.0232x; 1.0232x over previous
//
#include <hip/hip_runtime.h>
#include <math.h>

#define NB 4
#define SEQ 8192
#define NT (NB*SEQ)        // 32768 tokens
#define HDIM 64
#define NST 16
#define NBLK 4
#define KCONV 16
#define DIN 128
#define PDIM 16            // head dim
#define NH 8
#define CDIM 160
#define EPROJ 296
#define CH 128             // chunk length
#define NC 64              // chunks per sequence

typedef __attribute__((ext_vector_type(8))) short short8;
typedef __attribute__((ext_vector_type(4))) float f32x4;

__device__ __forceinline__ float sigf(float x){ return 1.0f/(1.0f+__expf(-x)); }

__device__ __forceinline__ unsigned short bf16r(float f){
  unsigned int u = __float_as_uint(f);
  u = (u + 0x7fffu + ((u >> 16) & 1u)) >> 16;
  return (unsigned short)u;
}
__device__ __forceinline__ unsigned int pk_bf16(float a, float b){
  return (unsigned int)bf16r(a) | ((unsigned int)bf16r(b) << 16);
}
__device__ __forceinline__ float bf16f(unsigned short h){
  return __uint_as_float(((unsigned int)h) << 16);
}

// h[t][d] = x[t] * w_in[d]
__global__ __launch_bounds__(256) void k_init_h(const float* __restrict__ x, const float* __restrict__ w_in,
                                                float* __restrict__ h){
  int i = blockIdx.x*256 + threadIdx.x;
  int t = i >> 6, d = i & 63;
  h[i] = x[t]*w_in[d];
}

// split all 4 layers' in_proj weights into bf16 hi/lo pair (once per call)
__global__ __launch_bounds__(256) void k_wsplit(const float* __restrict__ w,
                                                unsigned short* __restrict__ whi,
                                                unsigned short* __restrict__ wlo){
  int i = blockIdx.x*256 + threadIdx.x;
  if(i < NBLK*EPROJ*HDIM){
    float f = w[i];
    unsigned short hi = bf16r(f);
    float fh = bf16f(hi);
    whi[i] = hi;
    wlo[i] = bf16r(f - fh);
  }
}

// in-proj via split-bf16 MFMA. Outputs split by consumer precision:
//   e in [0,128)    -> zxz bf16 (z gate; consumer rounds to bf16 anyway)
//   e in [128,296)  -> zxc fp32 (conv inputs + raw dt: precision-critical; R15's
//                     bf16 conv-in regressed — unpack VALU > byte savings)
__global__ __launch_bounds__(256) void k_inproj(const float* __restrict__ h,
                                                const unsigned short* __restrict__ whi,
                                                const unsigned short* __restrict__ wlo,
                                                unsigned short* __restrict__ zxz,
                                                float* __restrict__ zxc){
  int tid = threadIdx.x;
  int lane = tid & 63, wid = tid >> 6;
  int quad = lane >> 4, lq = lane & 15;
  int t0 = blockIdx.x*64 + wid*16;

  const float* hp = h + (size_t)(t0+lq)*HDIM;
  short8 bh[2], bl[2];
#pragma unroll
  for(int kb=0;kb<2;kb++){
    float4 f0 = *(const float4*)(hp + kb*32 + quad*8);
    float4 f1 = *(const float4*)(hp + kb*32 + quad*8 + 4);
    float v[8] = {f0.x,f0.y,f0.z,f0.w,f1.x,f1.y,f1.z,f1.w};
#pragma unroll
    for(int j=0;j<8;j++){
      unsigned short hi = bf16r(v[j]);
      bh[kb][j] = (short)hi;
      bl[kb][j] = (short)bf16r(v[j] - bf16f(hi));
    }
  }

  for(int et=0; et<19; et++){
    int e_a = et*16 + lq;
    int ec = (e_a < EPROJ) ? e_a : (EPROJ-1);
    const unsigned short* wh = whi + (size_t)ec*HDIM + quad*8;
    const unsigned short* wl = wlo + (size_t)ec*HDIM + quad*8;
    short8 ah0 = *(const short8*)wh;
    short8 ah1 = *(const short8*)(wh + 32);
    short8 al0 = *(const short8*)wl;
    short8 al1 = *(const short8*)(wl + 32);
    f32x4 acc = {0.f,0.f,0.f,0.f};
    acc = __builtin_amdgcn_mfma_f32_16x16x32_bf16(ah0, bh[0], acc, 0, 0, 0);
    acc = __builtin_amdgcn_mfma_f32_16x16x32_bf16(ah1, bh[1], acc, 0, 0, 0);
    acc = __builtin_amdgcn_mfma_f32_16x16x32_bf16(ah0, bl[0], acc, 0, 0, 0);
    acc = __builtin_amdgcn_mfma_f32_16x16x32_bf16(ah1, bl[1], acc, 0, 0, 0);
    acc = __builtin_amdgcn_mfma_f32_16x16x32_bf16(al0, bh[0], acc, 0, 0, 0);
    acc = __builtin_amdgcn_mfma_f32_16x16x32_bf16(al1, bh[1], acc, 0, 0, 0);
#pragma unroll
    for(int r=0;r<4;r++){
      int e = et*16 + quad*4 + r;
      if(e < 128)        zxz[(size_t)e*NT + t0 + lq] = bf16r(acc[r]);
      else if(e < EPROJ) zxc[(size_t)(e-128)*NT + t0 + lq] = acc[r];
    }
  }
}

// Fused mid-section per (b,chunk): conv+silu -> xbc bf16 (+LDS hi/lo), dt softplus,
// per-head cumsum, chunk-states via split-bf16 MFMA.
__global__ __launch_bounds__(512) void k_mid(const float* __restrict__ zxc,
                                             const float* __restrict__ cw, const float* __restrict__ cb,
                                             const float* __restrict__ dtb, const float* __restrict__ alog,
                                             unsigned short* __restrict__ xbc, float* __restrict__ dt,
                                             float* __restrict__ acs, float* __restrict__ asum,
                                             float* __restrict__ S){
  __shared__ unsigned short XhT[128][136];
  __shared__ unsigned short XlT[128][136];
  __shared__ unsigned short BhT[16][136];
  __shared__ unsigned short BlT[16][136];
  __shared__ float dtl[8][128];
  __shared__ float wle[8][128];

  int bc = blockIdx.x;
  int c = bc & 63, b = bc >> 6;
  int t0 = b*SEQ + c*CH;
  int tid = threadIdx.x;

  // ---- conv + silu: 5 groups of 8 outputs per thread ----
  for(int it=0; it<5; it++){
    int G = tid + it*512;            // 0..2559 (160 ch x 16 groups)
    int ch = G >> 4;
    int sg = (G & 15) * 8;
    const float* p = zxc + (size_t)ch*NT + t0 + sg - 16;
    float buf[24];
    if(c == 0 && sg < 16){
#pragma unroll
      for(int j=0;j<24;j++){
        int l = sg - 16 + j;
        buf[j] = (l >= 0) ? p[j] : 0.f;
      }
    } else {
#pragma unroll
      for(int q4=0;q4<6;q4++){
        float4 f = *(const float4*)(p + q4*4);
        buf[q4*4+0]=f.x; buf[q4*4+1]=f.y; buf[q4*4+2]=f.z; buf[q4*4+3]=f.w;
      }
    }
    float wv[16];
#pragma unroll
    for(int k=0;k<16;k++) wv[k] = cw[ch*KCONV+k];
    float bias = cb[ch];
    unsigned short hs[8];
#pragma unroll
    for(int s=0;s<8;s++){
      float acc = bias;
#pragma unroll
      for(int k=0;k<16;k++) acc += wv[k]*buf[s+1+k];
      float r = acc * sigf(acc);
      unsigned short hi = bf16r(r);
      unsigned short lo = bf16r(r - bf16f(hi));
      hs[s] = hi;
      if(ch < 128){ XhT[ch][sg+s] = hi; XlT[ch][sg+s] = lo; }
      else if(ch < 144){ BhT[ch-128][sg+s] = hi; BlT[ch-128][sg+s] = lo; }
    }
    uint4 pk;
    pk.x = (unsigned int)hs[0] | ((unsigned int)hs[1] << 16);
    pk.y = (unsigned int)hs[2] | ((unsigned int)hs[3] << 16);
    pk.z = (unsigned int)hs[4] | ((unsigned int)hs[5] << 16);
    pk.w = (unsigned int)hs[6] | ((unsigned int)hs[7] << 16);
    *(uint4*)(xbc + (size_t)ch*NT + t0 + sg) = pk;
  }
  // ---- dt softplus ----
#pragma unroll
  for(int k=0;k<2;k++){
    int idx = tid + k*512;
    int hh = idx >> 7, s = idx & 127;
    float raw = zxc[(size_t)(CDIM + hh)*NT + t0 + s] + dtb[hh];
    float v = (raw > 20.f) ? raw : log1pf(__expf(raw));
    dtl[hh][s] = v;
    dt[(size_t)hh*NT + t0 + s] = v;
  }
  __syncthreads();

  int lane = tid & 63, wid = tid >> 6;
  {
    int hh = wid;
    float A = -__expf(alog[hh]);
    float d0 = dtl[hh][2*lane], d1 = dtl[hh][2*lane+1];
    float v0 = d0*A, v1 = d1*A;
    float s = v0 + v1;
    for(int off=1; off<64; off<<=1){
      float o = __shfl_up(s, off);
      if(lane >= off) s += o;
    }
    float tot = __shfl(s, 63);
    float excl = s - (v0+v1);
    float a0 = excl+v0, a1 = excl+v0+v1;
    *(float2*)&acs[(size_t)hh*NT + t0 + 2*lane] = make_float2(a0, a1);
    if(lane == 63) asum[(size_t)bc*NH + hh] = tot;
    wle[hh][2*lane]   = d0*__expf(tot - a0);
    wle[hh][2*lane+1] = d1*__expf(tot - a1);
  }
  __syncthreads();

  {
    int hh = wid;
    int lq = lane & 15, quad = lane >> 4;
    f32x4 acc = {0.f,0.f,0.f,0.f};
#pragma unroll
    for(int kb=0;kb<4;kb++){
      int k0 = kb*32 + quad*8;
      short8 xh = *(const short8*)&XhT[hh*16 + lq][k0];
      short8 xl = *(const short8*)&XlT[hh*16 + lq][k0];
      short8 ah, al;
#pragma unroll
      for(int j=0;j<8;j++){
        float xv = bf16f((unsigned short)xh[j]) + bf16f((unsigned short)xl[j]);
        float pw = xv * wle[hh][k0 + j];
        unsigned short hi = bf16r(pw);
        ah[j] = (short)hi;
        al[j] = (short)bf16r(pw - bf16f(hi));
      }
      short8 bh = *(const short8*)&BhT[lq][k0];
      short8 bl = *(const short8*)&BlT[lq][k0];
      acc = __builtin_amdgcn_mfma_f32_16x16x32_bf16(ah, bh, acc, 0, 0, 0);
      acc = __builtin_amdgcn_mfma_f32_16x16x32_bf16(ah, bl, acc, 0, 0, 0);
      acc = __builtin_amdgcn_mfma_f32_16x16x32_bf16(al, bh, acc, 0, 0, 0);
    }
    float* Sp = S + ((size_t)bc*NH + hh)*256;
#pragma unroll
    for(int r=0;r<4;r++) Sp[(quad*4 + r)*16 + lq] = acc[r];
  }
}

// sequential inter-chunk scan; 4-deep rolling prefetch.
__global__ __launch_bounds__(64) void k_scan(const float* __restrict__ S, const float* __restrict__ asum,
                                             const float* __restrict__ init, float* __restrict__ prev){
  int q  = blockIdx.x & 3;
  int hh = (blockIdx.x >> 2) & 7;
  int b  = blockIdx.x >> 5;
  int el = q*64 + threadIdx.x;
  const size_t cs = (size_t)NH*256;
  const float* Sp = S + ((size_t)(b*NC)*NH + hh)*256 + el;
  float* Pp = prev + ((size_t)(b*NC)*NH + hh)*256 + el;
  const float* ap = asum + (size_t)(b*NC)*NH + hh;
  float r = init[hh*256 + el];
  float s0 = Sp[0], s1 = Sp[cs], s2 = Sp[2*cs], s3 = Sp[3*cs];
  for(int c=0;c<NC;c+=4){
    Pp[(size_t)c*cs] = r;
    r = __expf(ap[(size_t)c*NH])*r + s0;
    s0 = (c+4 < NC) ? Sp[(size_t)(c+4)*cs] : 0.f;
    Pp[(size_t)(c+1)*cs] = r;
    r = __expf(ap[(size_t)(c+1)*NH])*r + s1;
    s1 = (c+5 < NC) ? Sp[(size_t)(c+5)*cs] : 0.f;
    Pp[(size_t)(c+2)*cs] = r;
    r = __expf(ap[(size_t)(c+2)*NH])*r + s2;
    s2 = (c+6 < NC) ? Sp[(size_t)(c+6)*cs] : 0.f;
    Pp[(size_t)(c+3)*cs] = r;
    r = __expf(ap[(size_t)(c+3)*NH])*r + s3;
    s3 = (c+7 < NC) ? Sp[(size_t)(c+7)*cs] : 0.f;
  }
}

// Fused tail per (b,chunk). Barrier-minimized (3 cross-wave crossings).
// last!=0: instead of h += (store), compute out[t] = sum_d h_new[d]*wout[d]
// in-register (shfl_xor reduce over lq) — folds k_final into the last layer.
__global__ __launch_bounds__(512) void k_tail(const unsigned short* __restrict__ xbc,
                                              const unsigned short* __restrict__ zxz,
                                              const float* __restrict__ dt, const float* __restrict__ acs,
                                              const float* __restrict__ prev, const float* __restrict__ dskip,
                                              const float* __restrict__ nw, const float* __restrict__ opw,
                                              const float* __restrict__ mw, const float* __restrict__ mb,
                                              float* __restrict__ h,
                                              int last, const float* __restrict__ wout,
                                              float* __restrict__ out){
  __shared__ __align__(16) unsigned char sm[142336];
  unsigned short* Bb   = (unsigned short*)(sm);             // [128][24]
  unsigned short* Cb   = (unsigned short*)(sm + 6144);      // [128][24]
  unsigned short* XbT  = (unsigned short*)(sm + 12288);     // [128][168]
  unsigned short* Sraw = (unsigned short*)(sm + 55296);     // [128][136]
  unsigned short* P    = (unsigned short*)(sm + 90112);     // [128][168]
  float* Al  = (float*)(sm + 133120);                       // [8][128]
  float* Dtl = (float*)(sm + 137216);                       // [8][128]
  float* nwl = (float*)(sm + 141312);                       // 128
  float* mbl = (float*)(sm + 141824);                       // 64
  unsigned short* zbuf = (unsigned short*)(sm + 142080);    // 16
  unsigned short* Wo = Sraw;                                // [64][136]
  unsigned short* Wm = Sraw + 64*136;                       // [64][72]
  unsigned short* Zb = XbT;                                 // [128][136]
  unsigned short* Yn = P;                                   // [128][136]
  unsigned short* Tt = P;                                   // [128][136] cols 0..63

  int bc = blockIdx.x;
  int c = bc & 63, b = bc >> 6;
  int t0 = b*SEQ + c*CH;
  int tid = threadIdx.x, lane = tid & 63, wid = tid >> 6;
  int quad = lane >> 4, lq = lane & 15;

  // ---- staging ----
#pragma unroll
  for(int k=0;k<8;k++){                 // B/C: 32ch x 128 (bf16 passthrough)
    int idx = tid + k*512;
    int ch = idx >> 7, s = idx & 127;
    unsigned short f = xbc[(size_t)(DIN+ch)*NT + t0 + s];
    if(ch < 16) Bb[s*24 + ch] = f;
    else        Cb[s*24 + ch-16] = f;
  }
#pragma unroll
  for(int k=0;k<8;k++){                 // X*dt: 128 x 128
    int fi = tid + k*512;
    int p = fi >> 5, s4 = fi & 31;
    uint2 xu = *(const uint2*)&xbc[(size_t)p*NT + t0 + s4*4];
    float4 dv = *(const float4*)&dt[(size_t)(p>>4)*NT + t0 + s4*4];
    float x0 = bf16f((unsigned short)(xu.x & 0xffffu));
    float x1 = bf16f((unsigned short)(xu.x >> 16));
    float x2 = bf16f((unsigned short)(xu.y & 0xffffu));
    float x3 = bf16f((unsigned short)(xu.y >> 16));
    *(unsigned int*)&XbT[p*168 + s4*4]   = pk_bf16(x0*dv.x, x1*dv.y);
    *(unsigned int*)&XbT[p*168 + s4*4+2] = pk_bf16(x2*dv.z, x3*dv.w);
  }
#pragma unroll
  for(int k=0;k<4;k++){                 // prev ext
    int idx = tid + k*512;
    int hh = idx >> 8, rest = idx & 255;
    int p = rest >> 4, n = rest & 15;
    XbT[(hh*16+p)*168 + 128 + n] = bf16r(prev[((size_t)bc*NH + hh)*256 + rest]);
  }
#pragma unroll
  for(int k=0;k<3;k++){                 // XbT pad 144..167
    int idx = tid + k*512;
    int p = idx / 12, cc = idx - p*12;
    *(unsigned int*)&XbT[p*168 + 144 + 2*cc] = 0u;
  }
#pragma unroll
  for(int k=0;k<2;k++){                 // Al / Dtl
    int idx = tid + k*512;
    int hh = idx >> 7, s = idx & 127;
    Al[hh*128+s]  = acs[(size_t)hh*NT + t0 + s];
    Dtl[hh*128+s] = dt[(size_t)hh*NT + t0 + s];
  }
  if(tid < 128) nwl[tid] = nw[tid];
  else if(tid < 192) mbl[tid-128] = mb[tid-128];
  else if(tid < 208) zbuf[tid-192] = 0;
  __syncthreads();                      // (1) staging visible to all waves

  // ---- score: S = C.B^T once, 16-row strip per wave (strip-private below) ----
  int strip = wid*16;
  short8 afr;
  {
    int row = strip + lq;
    const unsigned short* ap = (quad < 2) ? &Cb[row*24 + quad*8] : zbuf;
    afr = *(const short8*)ap;
  }
  for(int nt=0;nt<8;nt++){
    const unsigned short* bp = (quad < 2) ? &Bb[(nt*16+lq)*24 + quad*8] : zbuf;
    short8 bfr = *(const short8*)bp;
    f32x4 acc = {0.f,0.f,0.f,0.f};
    acc = __builtin_amdgcn_mfma_f32_16x16x32_bf16(afr, bfr, acc, 0, 0, 0);
#pragma unroll
    for(int r=0;r<4;r++)
      Sraw[(strip+quad*4+r)*136 + nt*16+lq] = bf16r(acc[r]);
  }
  // no barrier: Sraw rows strip-private

  // ---- per-head: P build + PV + D-skip (P rows strip-private) ----
  f32x4 accv[8];
  int c0 = 2*lane, c1 = 2*lane+1;
  for(int hh2=0; hh2<8; hh2++){
    const float* Alh = Al + hh2*128;
    const float* Dth = Dtl + hh2*128;
    float as0 = Alh[c0], as1 = Alh[c1];
#pragma unroll
    for(int rr=0;rr<16;rr++){
      int row = strip + rr;
      float alr = Alh[row];
      unsigned int sv = *(unsigned int*)&Sraw[row*136 + c0];
      float s0 = bf16f((unsigned short)(sv & 0xffffu));
      float s1 = bf16f((unsigned short)(sv >> 16));
      float p0 = s0 * __expf(alr - as0);     // dt NOT applied: already in XbT (x*dt)
      float p1 = s1 * __expf(alr - as1);
      p0 = (c0 <= row) ? p0 : 0.f;
      p1 = (c1 <= row) ? p1 : 0.f;
      *(unsigned int*)&P[row*168 + c0] = pk_bf16(p0, p1);
    }
    {   // ext cols 128..143: C[row][n]*exp(Al[row])
      int n = lane & 15, rg = lane >> 4;
#pragma unroll
      for(int rr=0;rr<4;rr++){
        int row = strip + rg*4 + rr;
        float ea = __expf(Alh[row]);
        P[row*168 + 128 + n] = bf16r(bf16f(Cb[row*24+n]) * ea);
      }
    }
    {   // pad cols 144..159 = 0
      int cc = lane & 7, rg = lane >> 3;
#pragma unroll
      for(int rr=0;rr<2;rr++){
        int row = strip + rg*2 + rr;
        *(unsigned int*)&P[row*168 + 144 + 2*cc] = 0u;
      }
    }
    f32x4 acc2 = {0.f,0.f,0.f,0.f};
#pragma unroll
    for(int ks=0;ks<5;ks++){
      short8 bfr = *(const short8*)&XbT[(hh2*16+lq)*168 + ks*32 + quad*8];
      short8 af  = *(const short8*)&P[(strip+lq)*168 + ks*32 + quad*8];
      acc2 = __builtin_amdgcn_mfma_f32_16x16x32_bf16(af, bfr, acc2, 0, 0, 0);
    }
    float Dk = dskip[hh2];
#pragma unroll
    for(int r=0;r<4;r++){
      int l = strip + quad*4 + r;
      float xdt = bf16f(XbT[(hh2*16+lq)*168 + l]);
      float dtv = fmaxf(Dth[l], 1e-30f);
      acc2[r] += Dk * xdt * __frcp_rn(dtv);
    }
    accv[hh2] = acc2;
  }
  __syncthreads();   // (2) WAR: all waves done reading XbT/Sraw before overwrite

  // ---- stage z (bf16 passthrough into XbT region), Wo/Wm (into Sraw region) ----
#pragma unroll
  for(int k=0;k<8;k++){
    int fi = tid + k*512;
    int p = fi >> 5, s4 = fi & 31;
    uint2 zu = *(const uint2*)&zxz[(size_t)p*NT + t0 + s4*4];
    *(unsigned int*)&Zb[p*136 + s4*4]   = zu.x;
    *(unsigned int*)&Zb[p*136 + s4*4+2] = zu.y;
  }
#pragma unroll
  for(int k=0;k<4;k++){
    int fi = tid + k*512;
    int n = fi >> 5, k4 = fi & 31;
    float4 wv = *(const float4*)&opw[(size_t)n*DIN + k4*4];
    *(unsigned int*)&Wo[n*136 + k4*4]   = pk_bf16(wv.x, wv.y);
    *(unsigned int*)&Wo[n*136 + k4*4+2] = pk_bf16(wv.z, wv.w);
  }
#pragma unroll
  for(int k=0;k<2;k++){
    int fi = tid + k*512;
    int n = fi >> 4, k4 = fi & 15;
    float4 wv = *(const float4*)&mw[(size_t)n*HDIM + k4*4];
    *(unsigned int*)&Wm[n*72 + k4*4]   = pk_bf16(wv.x, wv.y);
    *(unsigned int*)&Wm[n*72 + k4*4+2] = pk_bf16(wv.z, wv.w);
  }
  __syncthreads();   // (3) Zb/Wo/Wm visible (read cross-strip below)

  // ---- gate by silu(z), RMS (shfl over lq), write y_norm bf16 ----
  float rms_[4];
#pragma unroll
  for(int r=0;r<4;r++){
    int l = strip + quad*4 + r;
    float part = 0.f;
#pragma unroll
    for(int hh2=0;hh2<8;hh2++){
      float zv = bf16f(Zb[(hh2*16+lq)*136 + l]);
      float g = zv * sigf(zv);
      float yv = accv[hh2][r] * g;
      accv[hh2][r] = yv;
      part += yv*yv;
    }
    part += __shfl_xor(part,1); part += __shfl_xor(part,2);
    part += __shfl_xor(part,4); part += __shfl_xor(part,8);
    rms_[r] = rsqrtf(part*(1.0f/128.0f) + 1e-5f);
  }
#pragma unroll
  for(int hh2=0;hh2<8;hh2++){
    float nwv = nwl[hh2*16+lq];
#pragma unroll
    for(int r=0;r<4;r++){
      int l = strip + quad*4 + r;
      Yn[l*136 + hh2*16+lq] = bf16r(accv[hh2][r]*rms_[r]*nwv);
    }
  }
  // no barrier: Yn rows strip-private

  // ---- out_proj: (128 x 64) = Yn (K=128) x Wo ----
  short8 afk[4];
#pragma unroll
  for(int ks=0;ks<4;ks++) afk[ks] = *(const short8*)&Yn[(strip+lq)*136 + ks*32 + quad*8];
  f32x4 aco[4];
#pragma unroll
  for(int nt=0;nt<4;nt++){ aco[nt] = (f32x4){0.f,0.f,0.f,0.f}; }
#pragma unroll
  for(int nt=0;nt<4;nt++){
#pragma unroll
    for(int ks=0;ks<4;ks++){
      short8 bfr = *(const short8*)&Wo[(nt*16+lq)*136 + ks*32 + quad*8];
      aco[nt] = __builtin_amdgcn_mfma_f32_16x16x32_bf16(afk[ks], bfr, aco[nt], 0, 0, 0);
    }
  }

  // softsign -> Tt
#pragma unroll
  for(int nt=0;nt<4;nt++){
#pragma unroll
    for(int r=0;r<4;r++){
      int l = strip + quad*4 + r;
      float o = aco[nt][r];
      Tt[l*136 + nt*16+lq] = bf16r(o * rsqrtf(1.0f + o*o));
    }
  }
  // no barrier: Tt rows strip-private

  // ---- mlp: (128 x 64) = Tt (K=64) x Wm ----
  f32x4 acm[4];
#pragma unroll
  for(int nt=0;nt<4;nt++){ acm[nt] = (f32x4){0.f,0.f,0.f,0.f}; }
#pragma unroll
  for(int ks=0;ks<2;ks++){
    short8 af = *(const short8*)&Tt[(strip+lq)*136 + ks*32 + quad*8];
#pragma unroll
    for(int nt=0;nt<4;nt++){
      short8 bfr = *(const short8*)&Wm[(nt*16+lq)*72 + ks*32 + quad*8];
      acm[nt] = __builtin_amdgcn_mfma_f32_16x16x32_bf16(af, bfr, acm[nt], 0, 0, 0);
    }
  }
  // ---- residual / final output ----
  if(!last){
#pragma unroll
    for(int nt=0;nt<4;nt++){
#pragma unroll
      for(int r=0;r<4;r++){
        int l = strip + quad*4 + r;
        int d = nt*16 + lq;
        size_t gi = (size_t)(t0+l)*HDIM + d;
        h[gi] += acm[nt][r] + mbl[d];
      }
    }
  } else {
    // fold k_final: out[t] = sum_d (h[t][d] + mlp + bias) * wout[d]
    float ps[4] = {0.f,0.f,0.f,0.f};
#pragma unroll
    for(int nt=0;nt<4;nt++){
      int d = nt*16 + lq;
      float wo = wout[d];
      float bias = mbl[d];
#pragma unroll
      for(int r=0;r<4;r++){
        int l = strip + quad*4 + r;
        size_t gi = (size_t)(t0+l)*HDIM + d;
        float hn = h[gi] + acm[nt][r] + bias;
        ps[r] += hn * wo;
      }
    }
#pragma unroll
    for(int r=0;r<4;r++){
      ps[r] += __shfl_xor(ps[r],1); ps[r] += __shfl_xor(ps[r],2);
      ps[r] += __shfl_xor(ps[r],4); ps[r] += __shfl_xor(ps[r],8);
    }
    if(lq == 0){
#pragma unroll
      for(int r=0;r<4;r++) out[t0 + strip + quad*4 + r] = ps[r];
    }
  }
}

extern "C" void kernel_launch(void* const* d_in, const int* in_sizes, int n_in,
                              void* d_out, int out_size, void* d_ws, size_t ws_size,
                              hipStream_t stream){
  const float* x          = (const float*)d_in[0];
  const float* w_in       = (const float*)d_in[1];
  const float* w_out      = (const float*)d_in[2];
  const float* in_proj_w  = (const float*)d_in[3];
  const float* conv_w     = (const float*)d_in[4];
  const float* conv_b     = (const float*)d_in[5];
  const float* dt_bias    = (const float*)d_in[6];
  const float* A_log      = (const float*)d_in[7];
  const float* D_skip     = (const float*)d_in[8];
  const float* init_st    = (const float*)d_in[9];
  const float* norm_w     = (const float*)d_in[10];
  const float* out_proj_w = (const float*)d_in[11];
  const float* mlp_w      = (const float*)d_in[12];
  const float* mlp_b      = (const float*)d_in[13];
  float* out = (float*)d_out;

  float* ws = (float*)d_ws;
  float* h    = ws; ws += (size_t)NT*HDIM;
  unsigned short* zxz = (unsigned short*)ws; ws += (size_t)(128*NT)/2;   // bf16 z
  float* zxc  = ws; ws += (size_t)168*NT;                                // fp32 conv-in + raw dt
  unsigned short* xbc = (unsigned short*)ws; ws += (size_t)(CDIM*NT)/2;  // bf16 conv out
  float* dt   = ws; ws += (size_t)NH*NT;
  float* acs  = ws; ws += (size_t)NH*NT;
  float* asum = ws; ws += (size_t)NB*NC*NH;
  float* S    = ws; ws += (size_t)NB*NC*NH*256;
  float* prev = ws; ws += (size_t)NB*NC*NH*256;
  unsigned short* whi = (unsigned short*)ws; ws += (size_t)(NBLK*EPROJ*HDIM)/2;
  unsigned short* wlo = (unsigned short*)ws; ws += (size_t)(NBLK*EPROJ*HDIM)/2;

  k_init_h<<<(NT*HDIM)/256, 256, 0, stream>>>(x, w_in, h);
  k_wsplit<<<(NBLK*EPROJ*HDIM + 255)/256, 256, 0, stream>>>(in_proj_w, whi, wlo);
  for(int i=0;i<NBLK;i++){
    k_inproj<<<NT/64, 256, 0, stream>>>(h, whi + (size_t)i*EPROJ*HDIM,
                                        wlo + (size_t)i*EPROJ*HDIM, zxz, zxc);
    k_mid   <<<NB*NC, 512, 0, stream>>>(zxc, conv_w + i*CDIM*KCONV, conv_b + i*CDIM,
                                        dt_bias + i*NH, A_log + i*NH,
                                        xbc, dt, acs, asum, S);
    k_scan  <<<NB*NH*4, 64, 0, stream>>>(S, asum, init_st + i*NH*256, prev);
    k_tail  <<<NB*NC, 512, 0, stream>>>(xbc, zxz, dt, acs, prev, D_skip + i*NH,
                                        norm_w + i*DIN, out_proj_w + i*HDIM*DIN,
                                        mlp_w + i*HDIM*HDIM, mlp_b + i*HDIM, h,
                                        (i == NBLK-1) ? 1 : 0, w_out, out);
  }
}

// Round 18
// 370.268 us; speedup vs baseline: 1.0481x; 1.0244x over previous
//
#include <hip/hip_runtime.h>
#include <math.h>

#define NB 4
#define SEQ 8192
#define NT (NB*SEQ)        // 32768 tokens
#define HDIM 64
#define NST 16
#define NBLK 4
#define KCONV 16
#define DIN 128
#define PDIM 16            // head dim
#define NH 8
#define CDIM 160
#define EPROJ 296
#define CH 128             // chunk length
#define NC 64              // chunks per sequence

typedef __attribute__((ext_vector_type(8))) short short8;
typedef __attribute__((ext_vector_type(4))) float f32x4;

__device__ __forceinline__ float sigf(float x){ return 1.0f/(1.0f+__expf(-x)); }

__device__ __forceinline__ unsigned short bf16r(float f){
  unsigned int u = __float_as_uint(f);
  u = (u + 0x7fffu + ((u >> 16) & 1u)) >> 16;
  return (unsigned short)u;
}
__device__ __forceinline__ unsigned int pk_bf16(float a, float b){
  return (unsigned int)bf16r(a) | ((unsigned int)bf16r(b) << 16);
}
__device__ __forceinline__ float bf16f(unsigned short h){
  return __uint_as_float(((unsigned int)h) << 16);
}

// h[t][d] = x[t] * w_in[d]
__global__ __launch_bounds__(256) void k_init_h(const float* __restrict__ x, const float* __restrict__ w_in,
                                                float* __restrict__ h){
  int i = blockIdx.x*256 + threadIdx.x;
  int t = i >> 6, d = i & 63;
  h[i] = x[t]*w_in[d];
}

// split all 4 layers' in_proj weights into bf16 hi/lo pair (once per call)
__global__ __launch_bounds__(256) void k_wsplit(const float* __restrict__ w,
                                                unsigned short* __restrict__ whi,
                                                unsigned short* __restrict__ wlo){
  int i = blockIdx.x*256 + threadIdx.x;
  if(i < NBLK*EPROJ*HDIM){
    float f = w[i];
    unsigned short hi = bf16r(f);
    float fh = bf16f(hi);
    whi[i] = hi;
    wlo[i] = bf16r(f - fh);
  }
}

// in-proj via split-bf16 MFMA. zxz bf16 (z gate), zxc fp32 (conv-in + raw dt).
__global__ __launch_bounds__(256) void k_inproj(const float* __restrict__ h,
                                                const unsigned short* __restrict__ whi,
                                                const unsigned short* __restrict__ wlo,
                                                unsigned short* __restrict__ zxz,
                                                float* __restrict__ zxc){
  int tid = threadIdx.x;
  int lane = tid & 63, wid = tid >> 6;
  int quad = lane >> 4, lq = lane & 15;
  int t0 = blockIdx.x*64 + wid*16;

  const float* hp = h + (size_t)(t0+lq)*HDIM;
  short8 bh[2], bl[2];
#pragma unroll
  for(int kb=0;kb<2;kb++){
    float4 f0 = *(const float4*)(hp + kb*32 + quad*8);
    float4 f1 = *(const float4*)(hp + kb*32 + quad*8 + 4);
    float v[8] = {f0.x,f0.y,f0.z,f0.w,f1.x,f1.y,f1.z,f1.w};
#pragma unroll
    for(int j=0;j<8;j++){
      unsigned short hi = bf16r(v[j]);
      bh[kb][j] = (short)hi;
      bl[kb][j] = (short)bf16r(v[j] - bf16f(hi));
    }
  }

  for(int et=0; et<19; et++){
    int e_a = et*16 + lq;
    int ec = (e_a < EPROJ) ? e_a : (EPROJ-1);
    const unsigned short* wh = whi + (size_t)ec*HDIM + quad*8;
    const unsigned short* wl = wlo + (size_t)ec*HDIM + quad*8;
    short8 ah0 = *(const short8*)wh;
    short8 ah1 = *(const short8*)(wh + 32);
    short8 al0 = *(const short8*)wl;
    short8 al1 = *(const short8*)(wl + 32);
    f32x4 acc = {0.f,0.f,0.f,0.f};
    acc = __builtin_amdgcn_mfma_f32_16x16x32_bf16(ah0, bh[0], acc, 0, 0, 0);
    acc = __builtin_amdgcn_mfma_f32_16x16x32_bf16(ah1, bh[1], acc, 0, 0, 0);
    acc = __builtin_amdgcn_mfma_f32_16x16x32_bf16(ah0, bl[0], acc, 0, 0, 0);
    acc = __builtin_amdgcn_mfma_f32_16x16x32_bf16(ah1, bl[1], acc, 0, 0, 0);
    acc = __builtin_amdgcn_mfma_f32_16x16x32_bf16(al0, bh[0], acc, 0, 0, 0);
    acc = __builtin_amdgcn_mfma_f32_16x16x32_bf16(al1, bh[1], acc, 0, 0, 0);
#pragma unroll
    for(int r=0;r<4;r++){
      int e = et*16 + quad*4 + r;
      if(e < 128)        zxz[(size_t)e*NT + t0 + lq] = bf16r(acc[r]);
      else if(e < EPROJ) zxc[(size_t)(e-128)*NT + t0 + lq] = acc[r];
    }
  }
}

// Fused mid-section per (b,chunk).
__global__ __launch_bounds__(512) void k_mid(const float* __restrict__ zxc,
                                             const float* __restrict__ cw, const float* __restrict__ cb,
                                             const float* __restrict__ dtb, const float* __restrict__ alog,
                                             unsigned short* __restrict__ xbc, float* __restrict__ dt,
                                             float* __restrict__ acs, float* __restrict__ asum,
                                             float* __restrict__ S){
  __shared__ unsigned short XhT[128][136];
  __shared__ unsigned short XlT[128][136];
  __shared__ unsigned short BhT[16][136];
  __shared__ unsigned short BlT[16][136];
  __shared__ float dtl[8][128];
  __shared__ float wle[8][128];

  int bc = blockIdx.x;
  int c = bc & 63, b = bc >> 6;
  int t0 = b*SEQ + c*CH;
  int tid = threadIdx.x;

  for(int it=0; it<5; it++){
    int G = tid + it*512;
    int ch = G >> 4;
    int sg = (G & 15) * 8;
    const float* p = zxc + (size_t)ch*NT + t0 + sg - 16;
    float buf[24];
    if(c == 0 && sg < 16){
#pragma unroll
      for(int j=0;j<24;j++){
        int l = sg - 16 + j;
        buf[j] = (l >= 0) ? p[j] : 0.f;
      }
    } else {
#pragma unroll
      for(int q4=0;q4<6;q4++){
        float4 f = *(const float4*)(p + q4*4);
        buf[q4*4+0]=f.x; buf[q4*4+1]=f.y; buf[q4*4+2]=f.z; buf[q4*4+3]=f.w;
      }
    }
    float wv[16];
#pragma unroll
    for(int k=0;k<16;k++) wv[k] = cw[ch*KCONV+k];
    float bias = cb[ch];
    unsigned short hs[8];
#pragma unroll
    for(int s=0;s<8;s++){
      float acc = bias;
#pragma unroll
      for(int k=0;k<16;k++) acc += wv[k]*buf[s+1+k];
      float r = acc * sigf(acc);
      unsigned short hi = bf16r(r);
      unsigned short lo = bf16r(r - bf16f(hi));
      hs[s] = hi;
      if(ch < 128){ XhT[ch][sg+s] = hi; XlT[ch][sg+s] = lo; }
      else if(ch < 144){ BhT[ch-128][sg+s] = hi; BlT[ch-128][sg+s] = lo; }
    }
    uint4 pk;
    pk.x = (unsigned int)hs[0] | ((unsigned int)hs[1] << 16);
    pk.y = (unsigned int)hs[2] | ((unsigned int)hs[3] << 16);
    pk.z = (unsigned int)hs[4] | ((unsigned int)hs[5] << 16);
    pk.w = (unsigned int)hs[6] | ((unsigned int)hs[7] << 16);
    *(uint4*)(xbc + (size_t)ch*NT + t0 + sg) = pk;
  }
#pragma unroll
  for(int k=0;k<2;k++){
    int idx = tid + k*512;
    int hh = idx >> 7, s = idx & 127;
    float raw = zxc[(size_t)(CDIM + hh)*NT + t0 + s] + dtb[hh];
    float v = (raw > 20.f) ? raw : log1pf(__expf(raw));
    dtl[hh][s] = v;
    dt[(size_t)hh*NT + t0 + s] = v;
  }
  __syncthreads();

  int lane = tid & 63, wid = tid >> 6;
  {
    int hh = wid;
    float A = -__expf(alog[hh]);
    float d0 = dtl[hh][2*lane], d1 = dtl[hh][2*lane+1];
    float v0 = d0*A, v1 = d1*A;
    float s = v0 + v1;
    for(int off=1; off<64; off<<=1){
      float o = __shfl_up(s, off);
      if(lane >= off) s += o;
    }
    float tot = __shfl(s, 63);
    float excl = s - (v0+v1);
    float a0 = excl+v0, a1 = excl+v0+v1;
    *(float2*)&acs[(size_t)hh*NT + t0 + 2*lane] = make_float2(a0, a1);
    if(lane == 63) asum[(size_t)bc*NH + hh] = tot;
    wle[hh][2*lane]   = d0*__expf(tot - a0);
    wle[hh][2*lane+1] = d1*__expf(tot - a1);
  }
  __syncthreads();

  {
    int hh = wid;
    int lq = lane & 15, quad = lane >> 4;
    f32x4 acc = {0.f,0.f,0.f,0.f};
#pragma unroll
    for(int kb=0;kb<4;kb++){
      int k0 = kb*32 + quad*8;
      short8 xh = *(const short8*)&XhT[hh*16 + lq][k0];
      short8 xl = *(const short8*)&XlT[hh*16 + lq][k0];
      short8 ah, al;
#pragma unroll
      for(int j=0;j<8;j++){
        float xv = bf16f((unsigned short)xh[j]) + bf16f((unsigned short)xl[j]);
        float pw = xv * wle[hh][k0 + j];
        unsigned short hi = bf16r(pw);
        ah[j] = (short)hi;
        al[j] = (short)bf16r(pw - bf16f(hi));
      }
      short8 bh = *(const short8*)&BhT[lq][k0];
      short8 bl = *(const short8*)&BlT[lq][k0];
      acc = __builtin_amdgcn_mfma_f32_16x16x32_bf16(ah, bh, acc, 0, 0, 0);
      acc = __builtin_amdgcn_mfma_f32_16x16x32_bf16(ah, bl, acc, 0, 0, 0);
      acc = __builtin_amdgcn_mfma_f32_16x16x32_bf16(al, bh, acc, 0, 0, 0);
    }
    float* Sp = S + ((size_t)bc*NH + hh)*256;
#pragma unroll
    for(int r=0;r<4;r++) Sp[(quad*4 + r)*16 + lq] = acc[r];
  }
}

// sequential inter-chunk scan; 4-deep rolling prefetch.
__global__ __launch_bounds__(64) void k_scan(const float* __restrict__ S, const float* __restrict__ asum,
                                             const float* __restrict__ init, float* __restrict__ prev){
  int q  = blockIdx.x & 3;
  int hh = (blockIdx.x >> 2) & 7;
  int b  = blockIdx.x >> 5;
  int el = q*64 + threadIdx.x;
  const size_t cs = (size_t)NH*256;
  const float* Sp = S + ((size_t)(b*NC)*NH + hh)*256 + el;
  float* Pp = prev + ((size_t)(b*NC)*NH + hh)*256 + el;
  const float* ap = asum + (size_t)(b*NC)*NH + hh;
  float r = init[hh*256 + el];
  float s0 = Sp[0], s1 = Sp[cs], s2 = Sp[2*cs], s3 = Sp[3*cs];
  for(int c=0;c<NC;c+=4){
    Pp[(size_t)c*cs] = r;
    r = __expf(ap[(size_t)c*NH])*r + s0;
    s0 = (c+4 < NC) ? Sp[(size_t)(c+4)*cs] : 0.f;
    Pp[(size_t)(c+1)*cs] = r;
    r = __expf(ap[(size_t)(c+1)*NH])*r + s1;
    s1 = (c+5 < NC) ? Sp[(size_t)(c+5)*cs] : 0.f;
    Pp[(size_t)(c+2)*cs] = r;
    r = __expf(ap[(size_t)(c+2)*NH])*r + s2;
    s2 = (c+6 < NC) ? Sp[(size_t)(c+6)*cs] : 0.f;
    Pp[(size_t)(c+3)*cs] = r;
    r = __expf(ap[(size_t)(c+3)*NH])*r + s3;
    s3 = (c+7 < NC) ? Sp[(size_t)(c+7)*cs] : 0.f;
  }
}

// Fused tail v3 per (b,chunk): scores in REGISTERS (Sraw eliminated), P double-
// buffered (P0/P1) with build(h+1) pipelined ahead of PV(h); pad cols zeroed once.
// 3 cross-wave barriers as before. last!=0 folds k_final.
__global__ __launch_bounds__(512) void k_tail(const unsigned short* __restrict__ xbc,
                                              const unsigned short* __restrict__ zxz,
                                              const float* __restrict__ dt, const float* __restrict__ acs,
                                              const float* __restrict__ prev, const float* __restrict__ dskip,
                                              const float* __restrict__ nw, const float* __restrict__ opw,
                                              const float* __restrict__ mw, const float* __restrict__ mb,
                                              float* __restrict__ h,
                                              int last, const float* __restrict__ wout,
                                              float* __restrict__ out){
  __shared__ __align__(16) unsigned char sm[150304];
  unsigned short* Bb   = (unsigned short*)(sm);             // [128][24]
  unsigned short* Cb   = (unsigned short*)(sm + 6144);      // [128][24]
  unsigned short* XbT  = (unsigned short*)(sm + 12288);     // [128][168]
  unsigned short* P0   = (unsigned short*)(sm + 55296);     // [128][168]
  unsigned short* P1   = (unsigned short*)(sm + 98304);     // [128][168]
  float* Al  = (float*)(sm + 141312);                       // [8][128]
  float* Dtl = (float*)(sm + 145408);                       // [8][128]
  float* nwl = (float*)(sm + 149504);                       // 128
  float* mbl = (float*)(sm + 150016);                       // 64
  unsigned short* zbuf = (unsigned short*)(sm + 150272);    // 16
  // epilogue region reuse:
  unsigned short* Zb = XbT;                                 // [128][136]
  unsigned short* Wo = P0;                                  // [64][136]
  unsigned short* Wm = P0 + 64*136;                         // [64][72]
  unsigned short* Yn = P1;                                  // [128][136]
  unsigned short* Tt = P1;                                  // [128][136] cols 0..63

  int bc = blockIdx.x;
  int c = bc & 63, b = bc >> 6;
  int t0 = b*SEQ + c*CH;
  int tid = threadIdx.x, lane = tid & 63, wid = tid >> 6;
  int quad = lane >> 4, lq = lane & 15;

  // ---- staging ----
#pragma unroll
  for(int k=0;k<8;k++){                 // B/C: 32ch x 128 (bf16 passthrough)
    int idx = tid + k*512;
    int ch = idx >> 7, s = idx & 127;
    unsigned short f = xbc[(size_t)(DIN+ch)*NT + t0 + s];
    if(ch < 16) Bb[s*24 + ch] = f;
    else        Cb[s*24 + ch-16] = f;
  }
#pragma unroll
  for(int k=0;k<8;k++){                 // X*dt: 128 x 128
    int fi = tid + k*512;
    int p = fi >> 5, s4 = fi & 31;
    uint2 xu = *(const uint2*)&xbc[(size_t)p*NT + t0 + s4*4];
    float4 dv = *(const float4*)&dt[(size_t)(p>>4)*NT + t0 + s4*4];
    float x0 = bf16f((unsigned short)(xu.x & 0xffffu));
    float x1 = bf16f((unsigned short)(xu.x >> 16));
    float x2 = bf16f((unsigned short)(xu.y & 0xffffu));
    float x3 = bf16f((unsigned short)(xu.y >> 16));
    *(unsigned int*)&XbT[p*168 + s4*4]   = pk_bf16(x0*dv.x, x1*dv.y);
    *(unsigned int*)&XbT[p*168 + s4*4+2] = pk_bf16(x2*dv.z, x3*dv.w);
  }
#pragma unroll
  for(int k=0;k<4;k++){                 // prev ext
    int idx = tid + k*512;
    int hh = idx >> 8, rest = idx & 255;
    int p = rest >> 4, n = rest & 15;
    XbT[(hh*16+p)*168 + 128 + n] = bf16r(prev[((size_t)bc*NH + hh)*256 + rest]);
  }
#pragma unroll
  for(int k=0;k<3;k++){                 // XbT pad 144..167
    int idx = tid + k*512;
    int p = idx / 12, cc = idx - p*12;
    *(unsigned int*)&XbT[p*168 + 144 + 2*cc] = 0u;
  }
#pragma unroll
  for(int k=0;k<2;k++){                 // Al / Dtl
    int idx = tid + k*512;
    int hh = idx >> 7, s = idx & 127;
    Al[hh*128+s]  = acs[(size_t)hh*NT + t0 + s];
    Dtl[hh*128+s] = dt[(size_t)hh*NT + t0 + s];
  }
  if(tid < 128) nwl[tid] = nw[tid];
  else if(tid < 192) mbl[tid-128] = mb[tid-128];
  else if(tid < 208) zbuf[tid-192] = 0;
  __syncthreads();                      // (1) staging visible to all waves

  int strip = wid*16;
  // ---- zero pad cols 144..167 of P0/P1 strip rows (once) ----
#pragma unroll
  for(int k=0;k<3;k++){
    int idx = lane + k*64;              // 0..191
    int rr = idx / 12, cc = idx - rr*12;
    *(unsigned int*)&P0[(strip+rr)*168 + 144 + 2*cc] = 0u;
    *(unsigned int*)&P1[(strip+rr)*168 + 144 + 2*cc] = 0u;
  }

  // ---- score: S = C.B^T once, kept in registers ----
  short8 afr;
  {
    int row = strip + lq;
    const unsigned short* ap = (quad < 2) ? &Cb[row*24 + quad*8] : zbuf;
    afr = *(const short8*)ap;
  }
  f32x4 sc[8];
#pragma unroll
  for(int nt=0;nt<8;nt++){
    const unsigned short* bp = (quad < 2) ? &Bb[(nt*16+lq)*24 + quad*8] : zbuf;
    short8 bfr = *(const short8*)bp;
    f32x4 acc = {0.f,0.f,0.f,0.f};
    sc[nt] = __builtin_amdgcn_mfma_f32_16x16x32_bf16(afr, bfr, acc, 0, 0, 0);
  }

  // ---- head loop: build P(h) from registers, pipelined with PV(h-1) ----
  f32x4 accv[8];
  // build(0)
  {
    const float* Alh = Al;
    unsigned short* Pb = P0;
    float alr[4];
#pragma unroll
    for(int r=0;r<4;r++) alr[r] = Alh[strip + quad*4 + r];
#pragma unroll
    for(int nt=0;nt<8;nt++){
      int col = nt*16 + lq;
      float alc = Alh[col];
#pragma unroll
      for(int r=0;r<4;r++){
        int row = strip + quad*4 + r;
        float p = sc[nt][r] * __expf(alr[r] - alc);
        p = (col <= row) ? p : 0.f;
        Pb[row*168 + col] = bf16r(p);
      }
    }
    int n = lane & 15, rg = lane >> 4;
#pragma unroll
    for(int rr=0;rr<4;rr++){
      int row = strip + rg*4 + rr;
      float ea = __expf(Alh[row]);
      Pb[row*168 + 128 + n] = bf16r(bf16f(Cb[row*24+n]) * ea);
    }
  }
  for(int hh2=0; hh2<8; hh2++){
    // build(hh2+1) ahead of PV(hh2)
    if(hh2 < 7){
      const float* Alh = Al + (hh2+1)*128;
      unsigned short* Pb = ((hh2+1)&1) ? P1 : P0;
      float alr[4];
#pragma unroll
      for(int r=0;r<4;r++) alr[r] = Alh[strip + quad*4 + r];
#pragma unroll
      for(int nt=0;nt<8;nt++){
        int col = nt*16 + lq;
        float alc = Alh[col];
#pragma unroll
        for(int r=0;r<4;r++){
          int row = strip + quad*4 + r;
          float p = sc[nt][r] * __expf(alr[r] - alc);
          p = (col <= row) ? p : 0.f;
          Pb[row*168 + col] = bf16r(p);
        }
      }
      int n = lane & 15, rg = lane >> 4;
#pragma unroll
      for(int rr=0;rr<4;rr++){
        int row = strip + rg*4 + rr;
        float ea = __expf(Alh[row]);
        Pb[row*168 + 128 + n] = bf16r(bf16f(Cb[row*24+n]) * ea);
      }
    }
    // PV(hh2)
    const unsigned short* Pb = (hh2&1) ? P1 : P0;
    f32x4 acc2 = {0.f,0.f,0.f,0.f};
#pragma unroll
    for(int ks=0;ks<5;ks++){
      short8 bfr = *(const short8*)&XbT[(hh2*16+lq)*168 + ks*32 + quad*8];
      short8 af  = *(const short8*)&Pb[(strip+lq)*168 + ks*32 + quad*8];
      acc2 = __builtin_amdgcn_mfma_f32_16x16x32_bf16(af, bfr, acc2, 0, 0, 0);
    }
    const float* Dth = Dtl + hh2*128;
    float Dk = dskip[hh2];
#pragma unroll
    for(int r=0;r<4;r++){
      int l = strip + quad*4 + r;
      float xdt = bf16f(XbT[(hh2*16+lq)*168 + l]);
      float dtv = fmaxf(Dth[l], 1e-30f);
      acc2[r] += Dk * xdt * __frcp_rn(dtv);
    }
    accv[hh2] = acc2;
  }
  __syncthreads();   // (2) WAR: all waves done reading XbT/P before overwrite

  // ---- stage z (into XbT region), Wo/Wm (into P0 region) ----
#pragma unroll
  for(int k=0;k<8;k++){
    int fi = tid + k*512;
    int p = fi >> 5, s4 = fi & 31;
    uint2 zu = *(const uint2*)&zxz[(size_t)p*NT + t0 + s4*4];
    *(unsigned int*)&Zb[p*136 + s4*4]   = zu.x;
    *(unsigned int*)&Zb[p*136 + s4*4+2] = zu.y;
  }
#pragma unroll
  for(int k=0;k<4;k++){
    int fi = tid + k*512;
    int n = fi >> 5, k4 = fi & 31;
    float4 wv = *(const float4*)&opw[(size_t)n*DIN + k4*4];
    *(unsigned int*)&Wo[n*136 + k4*4]   = pk_bf16(wv.x, wv.y);
    *(unsigned int*)&Wo[n*136 + k4*4+2] = pk_bf16(wv.z, wv.w);
  }
#pragma unroll
  for(int k=0;k<2;k++){
    int fi = tid + k*512;
    int n = fi >> 4, k4 = fi & 15;
    float4 wv = *(const float4*)&mw[(size_t)n*HDIM + k4*4];
    *(unsigned int*)&Wm[n*72 + k4*4]   = pk_bf16(wv.x, wv.y);
    *(unsigned int*)&Wm[n*72 + k4*4+2] = pk_bf16(wv.z, wv.w);
  }
  __syncthreads();   // (3) Zb/Wo/Wm visible (read cross-strip below)

  // ---- gate by silu(z), RMS (shfl over lq), write y_norm bf16 ----
  float rms_[4];
#pragma unroll
  for(int r=0;r<4;r++){
    int l = strip + quad*4 + r;
    float part = 0.f;
#pragma unroll
    for(int hh2=0;hh2<8;hh2++){
      float zv = bf16f(Zb[(hh2*16+lq)*136 + l]);
      float g = zv * sigf(zv);
      float yv = accv[hh2][r] * g;
      accv[hh2][r] = yv;
      part += yv*yv;
    }
    part += __shfl_xor(part,1); part += __shfl_xor(part,2);
    part += __shfl_xor(part,4); part += __shfl_xor(part,8);
    rms_[r] = rsqrtf(part*(1.0f/128.0f) + 1e-5f);
  }
#pragma unroll
  for(int hh2=0;hh2<8;hh2++){
    float nwv = nwl[hh2*16+lq];
#pragma unroll
    for(int r=0;r<4;r++){
      int l = strip + quad*4 + r;
      Yn[l*136 + hh2*16+lq] = bf16r(accv[hh2][r]*rms_[r]*nwv);
    }
  }
  // no barrier: Yn rows strip-private

  // ---- out_proj: (128 x 64) = Yn (K=128) x Wo ----
  short8 afk[4];
#pragma unroll
  for(int ks=0;ks<4;ks++) afk[ks] = *(const short8*)&Yn[(strip+lq)*136 + ks*32 + quad*8];
  f32x4 aco[4];
#pragma unroll
  for(int nt=0;nt<4;nt++){ aco[nt] = (f32x4){0.f,0.f,0.f,0.f}; }
#pragma unroll
  for(int nt=0;nt<4;nt++){
#pragma unroll
    for(int ks=0;ks<4;ks++){
      short8 bfr = *(const short8*)&Wo[(nt*16+lq)*136 + ks*32 + quad*8];
      aco[nt] = __builtin_amdgcn_mfma_f32_16x16x32_bf16(afk[ks], bfr, aco[nt], 0, 0, 0);
    }
  }

  // softsign -> Tt
#pragma unroll
  for(int nt=0;nt<4;nt++){
#pragma unroll
    for(int r=0;r<4;r++){
      int l = strip + quad*4 + r;
      float o = aco[nt][r];
      Tt[l*136 + nt*16+lq] = bf16r(o * rsqrtf(1.0f + o*o));
    }
  }
  // no barrier: Tt rows strip-private

  // ---- mlp: (128 x 64) = Tt (K=64) x Wm ----
  f32x4 acm[4];
#pragma unroll
  for(int nt=0;nt<4;nt++){ acm[nt] = (f32x4){0.f,0.f,0.f,0.f}; }
#pragma unroll
  for(int ks=0;ks<2;ks++){
    short8 af = *(const short8*)&Tt[(strip+lq)*136 + ks*32 + quad*8];
#pragma unroll
    for(int nt=0;nt<4;nt++){
      short8 bfr = *(const short8*)&Wm[(nt*16+lq)*72 + ks*32 + quad*8];
      acm[nt] = __builtin_amdgcn_mfma_f32_16x16x32_bf16(af, bfr, acm[nt], 0, 0, 0);
    }
  }
  // ---- residual / final output ----
  if(!last){
#pragma unroll
    for(int nt=0;nt<4;nt++){
#pragma unroll
      for(int r=0;r<4;r++){
        int l = strip + quad*4 + r;
        int d = nt*16 + lq;
        size_t gi = (size_t)(t0+l)*HDIM + d;
        h[gi] += acm[nt][r] + mbl[d];
      }
    }
  } else {
    float ps[4] = {0.f,0.f,0.f,0.f};
#pragma unroll
    for(int nt=0;nt<4;nt++){
      int d = nt*16 + lq;
      float wo = wout[d];
      float bias = mbl[d];
#pragma unroll
      for(int r=0;r<4;r++){
        int l = strip + quad*4 + r;
        size_t gi = (size_t)(t0+l)*HDIM + d;
        float hn = h[gi] + acm[nt][r] + bias;
        ps[r] += hn * wo;
      }
    }
#pragma unroll
    for(int r=0;r<4;r++){
      ps[r] += __shfl_xor(ps[r],1); ps[r] += __shfl_xor(ps[r],2);
      ps[r] += __shfl_xor(ps[r],4); ps[r] += __shfl_xor(ps[r],8);
    }
    if(lq == 0){
#pragma unroll
      for(int r=0;r<4;r++) out[t0 + strip + quad*4 + r] = ps[r];
    }
  }
}

extern "C" void kernel_launch(void* const* d_in, const int* in_sizes, int n_in,
                              void* d_out, int out_size, void* d_ws, size_t ws_size,
                              hipStream_t stream){
  const float* x          = (const float*)d_in[0];
  const float* w_in       = (const float*)d_in[1];
  const float* w_out      = (const float*)d_in[2];
  const float* in_proj_w  = (const float*)d_in[3];
  const float* conv_w     = (const float*)d_in[4];
  const float* conv_b     = (const float*)d_in[5];
  const float* dt_bias    = (const float*)d_in[6];
  const float* A_log      = (const float*)d_in[7];
  const float* D_skip     = (const float*)d_in[8];
  const float* init_st    = (const float*)d_in[9];
  const float* norm_w     = (const float*)d_in[10];
  const float* out_proj_w = (const float*)d_in[11];
  const float* mlp_w      = (const float*)d_in[12];
  const float* mlp_b      = (const float*)d_in[13];
  float* out = (float*)d_out;

  float* ws = (float*)d_ws;
  float* h    = ws; ws += (size_t)NT*HDIM;
  unsigned short* zxz = (unsigned short*)ws; ws += (size_t)(128*NT)/2;   // bf16 z
  float* zxc  = ws; ws += (size_t)168*NT;                                // fp32 conv-in + raw dt
  unsigned short* xbc = (unsigned short*)ws; ws += (size_t)(CDIM*NT)/2;  // bf16 conv out
  float* dt   = ws; ws += (size_t)NH*NT;
  float* acs  = ws; ws += (size_t)NH*NT;
  float* asum = ws; ws += (size_t)NB*NC*NH;
  float* S    = ws; ws += (size_t)NB*NC*NH*256;
  float* prev = ws; ws += (size_t)NB*NC*NH*256;
  unsigned short* whi = (unsigned short*)ws; ws += (size_t)(NBLK*EPROJ*HDIM)/2;
  unsigned short* wlo = (unsigned short*)ws; ws += (size_t)(NBLK*EPROJ*HDIM)/2;

  k_init_h<<<(NT*HDIM)/256, 256, 0, stream>>>(x, w_in, h);
  k_wsplit<<<(NBLK*EPROJ*HDIM + 255)/256, 256, 0, stream>>>(in_proj_w, whi, wlo);
  for(int i=0;i<NBLK;i++){
    k_inproj<<<NT/64, 256, 0, stream>>>(h, whi + (size_t)i*EPROJ*HDIM,
                                        wlo + (size_t)i*EPROJ*HDIM, zxz, zxc);
    k_mid   <<<NB*NC, 512, 0, stream>>>(zxc, conv_w + i*CDIM*KCONV, conv_b + i*CDIM,
                                        dt_bias + i*NH, A_log + i*NH,
                                        xbc, dt, acs, asum, S);
    k_scan  <<<NB*NH*4, 64, 0, stream>>>(S, asum, init_st + i*NH*256, prev);
    k_tail  <<<NB*NC, 512, 0, stream>>>(xbc, zxz, dt, acs, prev, D_skip + i*NH,
                                        norm_w + i*DIN, out_proj_w + i*HDIM*DIN,
                                        mlp_w + i*HDIM*HDIM, mlp_b + i*HDIM, h,
                                        (i == NBLK-1) ? 1 : 0, w_out, out);
  }
}

// Round 19
// 363.744 us; speedup vs baseline: 1.0669x; 1.0179x over previous
//
#include <hip/hip_runtime.h>
#include <math.h>

#define NB 4
#define SEQ 8192
#define NT (NB*SEQ)        // 32768 tokens
#define HDIM 64
#define NST 16
#define NBLK 4
#define KCONV 16
#define DIN 128
#define PDIM 16            // head dim
#define NH 8
#define CDIM 160
#define EPROJ 296
#define CH 128             // chunk length
#define NC 64              // chunks per sequence

typedef __attribute__((ext_vector_type(8))) short short8;
typedef __attribute__((ext_vector_type(4))) float f32x4;

__device__ __forceinline__ float sigf(float x){ return 1.0f/(1.0f+__expf(-x)); }

__device__ __forceinline__ unsigned short bf16r(float f){
  unsigned int u = __float_as_uint(f);
  u = (u + 0x7fffu + ((u >> 16) & 1u)) >> 16;
  return (unsigned short)u;
}
__device__ __forceinline__ unsigned int pk_bf16(float a, float b){
  return (unsigned int)bf16r(a) | ((unsigned int)bf16r(b) << 16);
}
__device__ __forceinline__ float bf16f(unsigned short h){
  return __uint_as_float(((unsigned int)h) << 16);
}

// h[t][d] = x[t] * w_in[d]
__global__ __launch_bounds__(256) void k_init_h(const float* __restrict__ x, const float* __restrict__ w_in,
                                                float* __restrict__ h){
  int i = blockIdx.x*256 + threadIdx.x;
  int t = i >> 6, d = i & 63;
  h[i] = x[t]*w_in[d];
}

// split all 4 layers' in_proj weights into bf16 hi/lo pair (once per call)
__global__ __launch_bounds__(256) void k_wsplit(const float* __restrict__ w,
                                                unsigned short* __restrict__ whi,
                                                unsigned short* __restrict__ wlo){
  int i = blockIdx.x*256 + threadIdx.x;
  if(i < NBLK*EPROJ*HDIM){
    float f = w[i];
    unsigned short hi = bf16r(f);
    float fh = bf16f(hi);
    whi[i] = hi;
    wlo[i] = bf16r(f - fh);
  }
}

// in-proj via split-bf16 MFMA. zxz bf16 (z gate), zxc fp32 (conv-in + raw dt).
__global__ __launch_bounds__(256) void k_inproj(const float* __restrict__ h,
                                                const unsigned short* __restrict__ whi,
                                                const unsigned short* __restrict__ wlo,
                                                unsigned short* __restrict__ zxz,
                                                float* __restrict__ zxc){
  int tid = threadIdx.x;
  int lane = tid & 63, wid = tid >> 6;
  int quad = lane >> 4, lq = lane & 15;
  int t0 = blockIdx.x*64 + wid*16;

  const float* hp = h + (size_t)(t0+lq)*HDIM;
  short8 bh[2], bl[2];
#pragma unroll
  for(int kb=0;kb<2;kb++){
    float4 f0 = *(const float4*)(hp + kb*32 + quad*8);
    float4 f1 = *(const float4*)(hp + kb*32 + quad*8 + 4);
    float v[8] = {f0.x,f0.y,f0.z,f0.w,f1.x,f1.y,f1.z,f1.w};
#pragma unroll
    for(int j=0;j<8;j++){
      unsigned short hi = bf16r(v[j]);
      bh[kb][j] = (short)hi;
      bl[kb][j] = (short)bf16r(v[j] - bf16f(hi));
    }
  }

  for(int et=0; et<19; et++){
    int e_a = et*16 + lq;
    int ec = (e_a < EPROJ) ? e_a : (EPROJ-1);
    const unsigned short* wh = whi + (size_t)ec*HDIM + quad*8;
    const unsigned short* wl = wlo + (size_t)ec*HDIM + quad*8;
    short8 ah0 = *(const short8*)wh;
    short8 ah1 = *(const short8*)(wh + 32);
    short8 al0 = *(const short8*)wl;
    short8 al1 = *(const short8*)(wl + 32);
    f32x4 acc = {0.f,0.f,0.f,0.f};
    acc = __builtin_amdgcn_mfma_f32_16x16x32_bf16(ah0, bh[0], acc, 0, 0, 0);
    acc = __builtin_amdgcn_mfma_f32_16x16x32_bf16(ah1, bh[1], acc, 0, 0, 0);
    acc = __builtin_amdgcn_mfma_f32_16x16x32_bf16(ah0, bl[0], acc, 0, 0, 0);
    acc = __builtin_amdgcn_mfma_f32_16x16x32_bf16(ah1, bl[1], acc, 0, 0, 0);
    acc = __builtin_amdgcn_mfma_f32_16x16x32_bf16(al0, bh[0], acc, 0, 0, 0);
    acc = __builtin_amdgcn_mfma_f32_16x16x32_bf16(al1, bh[1], acc, 0, 0, 0);
#pragma unroll
    for(int r=0;r<4;r++){
      int e = et*16 + quad*4 + r;
      if(e < 128)        zxz[(size_t)e*NT + t0 + lq] = bf16r(acc[r]);
      else if(e < EPROJ) zxc[(size_t)(e-128)*NT + t0 + lq] = acc[r];
    }
  }
}

// Fused mid-section per (b,chunk).
__global__ __launch_bounds__(512) void k_mid(const float* __restrict__ zxc,
                                             const float* __restrict__ cw, const float* __restrict__ cb,
                                             const float* __restrict__ dtb, const float* __restrict__ alog,
                                             unsigned short* __restrict__ xbc, float* __restrict__ dt,
                                             float* __restrict__ acs, float* __restrict__ asum,
                                             float* __restrict__ S){
  __shared__ unsigned short XhT[128][136];
  __shared__ unsigned short XlT[128][136];
  __shared__ unsigned short BhT[16][136];
  __shared__ unsigned short BlT[16][136];
  __shared__ float dtl[8][128];
  __shared__ float wle[8][128];

  int bc = blockIdx.x;
  int c = bc & 63, b = bc >> 6;
  int t0 = b*SEQ + c*CH;
  int tid = threadIdx.x;

  for(int it=0; it<5; it++){
    int G = tid + it*512;
    int ch = G >> 4;
    int sg = (G & 15) * 8;
    const float* p = zxc + (size_t)ch*NT + t0 + sg - 16;
    float buf[24];
    if(c == 0 && sg < 16){
#pragma unroll
      for(int j=0;j<24;j++){
        int l = sg - 16 + j;
        buf[j] = (l >= 0) ? p[j] : 0.f;
      }
    } else {
#pragma unroll
      for(int q4=0;q4<6;q4++){
        float4 f = *(const float4*)(p + q4*4);
        buf[q4*4+0]=f.x; buf[q4*4+1]=f.y; buf[q4*4+2]=f.z; buf[q4*4+3]=f.w;
      }
    }
    float wv[16];
#pragma unroll
    for(int k=0;k<16;k++) wv[k] = cw[ch*KCONV+k];
    float bias = cb[ch];
    unsigned short hs[8];
#pragma unroll
    for(int s=0;s<8;s++){
      float acc = bias;
#pragma unroll
      for(int k=0;k<16;k++) acc += wv[k]*buf[s+1+k];
      float r = acc * sigf(acc);
      unsigned short hi = bf16r(r);
      unsigned short lo = bf16r(r - bf16f(hi));
      hs[s] = hi;
      if(ch < 128){ XhT[ch][sg+s] = hi; XlT[ch][sg+s] = lo; }
      else if(ch < 144){ BhT[ch-128][sg+s] = hi; BlT[ch-128][sg+s] = lo; }
    }
    uint4 pk;
    pk.x = (unsigned int)hs[0] | ((unsigned int)hs[1] << 16);
    pk.y = (unsigned int)hs[2] | ((unsigned int)hs[3] << 16);
    pk.z = (unsigned int)hs[4] | ((unsigned int)hs[5] << 16);
    pk.w = (unsigned int)hs[6] | ((unsigned int)hs[7] << 16);
    *(uint4*)(xbc + (size_t)ch*NT + t0 + sg) = pk;
  }
#pragma unroll
  for(int k=0;k<2;k++){
    int idx = tid + k*512;
    int hh = idx >> 7, s = idx & 127;
    float raw = zxc[(size_t)(CDIM + hh)*NT + t0 + s] + dtb[hh];
    float v = (raw > 20.f) ? raw : log1pf(__expf(raw));
    dtl[hh][s] = v;
    dt[(size_t)hh*NT + t0 + s] = v;
  }
  __syncthreads();

  int lane = tid & 63, wid = tid >> 6;
  {
    int hh = wid;
    float A = -__expf(alog[hh]);
    float d0 = dtl[hh][2*lane], d1 = dtl[hh][2*lane+1];
    float v0 = d0*A, v1 = d1*A;
    float s = v0 + v1;
    for(int off=1; off<64; off<<=1){
      float o = __shfl_up(s, off);
      if(lane >= off) s += o;
    }
    float tot = __shfl(s, 63);
    float excl = s - (v0+v1);
    float a0 = excl+v0, a1 = excl+v0+v1;
    *(float2*)&acs[(size_t)hh*NT + t0 + 2*lane] = make_float2(a0, a1);
    if(lane == 63) asum[(size_t)bc*NH + hh] = tot;
    wle[hh][2*lane]   = d0*__expf(tot - a0);
    wle[hh][2*lane+1] = d1*__expf(tot - a1);
  }
  __syncthreads();

  {
    int hh = wid;
    int lq = lane & 15, quad = lane >> 4;
    f32x4 acc = {0.f,0.f,0.f,0.f};
#pragma unroll
    for(int kb=0;kb<4;kb++){
      int k0 = kb*32 + quad*8;
      short8 xh = *(const short8*)&XhT[hh*16 + lq][k0];
      short8 xl = *(const short8*)&XlT[hh*16 + lq][k0];
      short8 ah, al;
#pragma unroll
      for(int j=0;j<8;j++){
        float xv = bf16f((unsigned short)xh[j]) + bf16f((unsigned short)xl[j]);
        float pw = xv * wle[hh][k0 + j];
        unsigned short hi = bf16r(pw);
        ah[j] = (short)hi;
        al[j] = (short)bf16r(pw - bf16f(hi));
      }
      short8 bh = *(const short8*)&BhT[lq][k0];
      short8 bl = *(const short8*)&BlT[lq][k0];
      acc = __builtin_amdgcn_mfma_f32_16x16x32_bf16(ah, bh, acc, 0, 0, 0);
      acc = __builtin_amdgcn_mfma_f32_16x16x32_bf16(ah, bl, acc, 0, 0, 0);
      acc = __builtin_amdgcn_mfma_f32_16x16x32_bf16(al, bh, acc, 0, 0, 0);
    }
    float* Sp = S + ((size_t)bc*NH + hh)*256;
#pragma unroll
    for(int r=0;r<4;r++) Sp[(quad*4 + r)*16 + lq] = acc[r];
  }
}

// sequential inter-chunk scan; 4-deep rolling prefetch.
__global__ __launch_bounds__(64) void k_scan(const float* __restrict__ S, const float* __restrict__ asum,
                                             const float* __restrict__ init, float* __restrict__ prev){
  int q  = blockIdx.x & 3;
  int hh = (blockIdx.x >> 2) & 7;
  int b  = blockIdx.x >> 5;
  int el = q*64 + threadIdx.x;
  const size_t cs = (size_t)NH*256;
  const float* Sp = S + ((size_t)(b*NC)*NH + hh)*256 + el;
  float* Pp = prev + ((size_t)(b*NC)*NH + hh)*256 + el;
  const float* ap = asum + (size_t)(b*NC)*NH + hh;
  float r = init[hh*256 + el];
  float s0 = Sp[0], s1 = Sp[cs], s2 = Sp[2*cs], s3 = Sp[3*cs];
  for(int c=0;c<NC;c+=4){
    Pp[(size_t)c*cs] = r;
    r = __expf(ap[(size_t)c*NH])*r + s0;
    s0 = (c+4 < NC) ? Sp[(size_t)(c+4)*cs] : 0.f;
    Pp[(size_t)(c+1)*cs] = r;
    r = __expf(ap[(size_t)(c+1)*NH])*r + s1;
    s1 = (c+5 < NC) ? Sp[(size_t)(c+5)*cs] : 0.f;
    Pp[(size_t)(c+2)*cs] = r;
    r = __expf(ap[(size_t)(c+2)*NH])*r + s2;
    s2 = (c+6 < NC) ? Sp[(size_t)(c+6)*cs] : 0.f;
    Pp[(size_t)(c+3)*cs] = r;
    r = __expf(ap[(size_t)(c+3)*NH])*r + s3;
    s3 = (c+7 < NC) ? Sp[(size_t)(c+7)*cs] : 0.f;
  }
}

// Fused tail v4 per (b,chunk): 1024 threads = 16 waves (4 waves/SIMD — 2x occupancy).
// Heads split across 2 wave-groups (g = wid>>3, heads 4g..4g+3), each group
// single-buffers its own P (P0/P1). Head loop barrier-free (strip-private).
// RMS combined cross-group via ssl[2][128]; rms applied post-out_proj-MFMA
// (row-constant factors out of the K-sum), pre-softsign.
__global__ __launch_bounds__(1024) void k_tail(const unsigned short* __restrict__ xbc,
                                               const unsigned short* __restrict__ zxz,
                                               const float* __restrict__ dt, const float* __restrict__ acs,
                                               const float* __restrict__ prev, const float* __restrict__ dskip,
                                               const float* __restrict__ nw, const float* __restrict__ opw,
                                               const float* __restrict__ mw, const float* __restrict__ mb,
                                               float* __restrict__ h,
                                               int last, const float* __restrict__ wout,
                                               float* __restrict__ out){
  __shared__ __align__(16) unsigned char sm[151840];
  unsigned short* Bb   = (unsigned short*)(sm);             // [128][24]
  unsigned short* Cb   = (unsigned short*)(sm + 6144);      // [128][24]
  unsigned short* XbT  = (unsigned short*)(sm + 12288);     // [128][168]
  unsigned short* P0   = (unsigned short*)(sm + 55296);     // [128][168] group0
  unsigned short* P1   = (unsigned short*)(sm + 98304);     // [128][168] group1
  float* Al  = (float*)(sm + 141312);                       // [8][128]
  float* Dtl = (float*)(sm + 145408);                       // [8][128]
  float* nwl = (float*)(sm + 149504);                       // 128
  float* mbl = (float*)(sm + 150016);                       // 64
  unsigned short* zbuf = (unsigned short*)(sm + 150272);    // 16
  float* ssl  = (float*)(sm + 150304);                      // [2][128]
  float* outb = (float*)(sm + 151328);                      // [128]
  // epilogue region reuse:
  unsigned short* Zb = XbT;                                 // [128][136]
  unsigned short* Wo = P0;                                  // [64][136]
  unsigned short* Wm = P0 + 64*136;                         // [64][72]
  unsigned short* Yn = P1;                                  // [128][136]
  unsigned short* Tt = P1;                                  // [128][136] cols 0..63

  int bc = blockIdx.x;
  int c = bc & 63, b = bc >> 6;
  int t0 = b*SEQ + c*CH;
  int tid = threadIdx.x, lane = tid & 63, wid = tid >> 6;
  int quad = lane >> 4, lq = lane & 15;
  int hgrp = wid >> 3;                  // 0 or 1
  int strip = (wid & 7)*16;

  // ---- staging (1024 threads) ----
#pragma unroll
  for(int k=0;k<4;k++){                 // B/C: 32ch x 128
    int idx = tid + k*1024;
    int ch = idx >> 7, s = idx & 127;
    unsigned short f = xbc[(size_t)(DIN+ch)*NT + t0 + s];
    if(ch < 16) Bb[s*24 + ch] = f;
    else        Cb[s*24 + ch-16] = f;
  }
#pragma unroll
  for(int k=0;k<4;k++){                 // X*dt: 128 x 128
    int fi = tid + k*1024;
    int p = fi >> 5, s4 = fi & 31;
    uint2 xu = *(const uint2*)&xbc[(size_t)p*NT + t0 + s4*4];
    float4 dv = *(const float4*)&dt[(size_t)(p>>4)*NT + t0 + s4*4];
    float x0 = bf16f((unsigned short)(xu.x & 0xffffu));
    float x1 = bf16f((unsigned short)(xu.x >> 16));
    float x2 = bf16f((unsigned short)(xu.y & 0xffffu));
    float x3 = bf16f((unsigned short)(xu.y >> 16));
    *(unsigned int*)&XbT[p*168 + s4*4]   = pk_bf16(x0*dv.x, x1*dv.y);
    *(unsigned int*)&XbT[p*168 + s4*4+2] = pk_bf16(x2*dv.z, x3*dv.w);
  }
#pragma unroll
  for(int k=0;k<2;k++){                 // prev ext
    int idx = tid + k*1024;
    int hh = idx >> 8, rest = idx & 255;
    int p = rest >> 4, n = rest & 15;
    XbT[(hh*16+p)*168 + 128 + n] = bf16r(prev[((size_t)bc*NH + hh)*256 + rest]);
  }
#pragma unroll
  for(int k=0;k<2;k++){                 // XbT pad 144..167
    int idx = tid + k*1024;
    if(idx < 1536){
      int p = idx / 12, cc = idx - p*12;
      *(unsigned int*)&XbT[p*168 + 144 + 2*cc] = 0u;
    }
  }
  {                                     // Al / Dtl
    int hh = tid >> 7, s = tid & 127;
    Al[hh*128+s]  = acs[(size_t)hh*NT + t0 + s];
    Dtl[hh*128+s] = dt[(size_t)hh*NT + t0 + s];
  }
  if(tid < 128) nwl[tid] = nw[tid];
  else if(tid < 192) mbl[tid-128] = mb[tid-128];
  else if(tid < 208) zbuf[tid-192] = 0;
  // zero pad cols 144..167 of own group's P strip rows
  {
    unsigned short* Pg = hgrp ? P1 : P0;
#pragma unroll
    for(int k=0;k<3;k++){
      int idx = lane + k*64;            // 0..191
      int rr = idx / 12, cc = idx - rr*12;
      *(unsigned int*)&Pg[(strip+rr)*168 + 144 + 2*cc] = 0u;
    }
  }
  __syncthreads();                      // (1) staging visible

  // ---- score: S = C.B^T, kept in registers (duplicated per group) ----
  short8 afr;
  {
    int row = strip + lq;
    const unsigned short* ap = (quad < 2) ? &Cb[row*24 + quad*8] : zbuf;
    afr = *(const short8*)ap;
  }
  f32x4 sc[8];
#pragma unroll
  for(int nt=0;nt<8;nt++){
    const unsigned short* bp = (quad < 2) ? &Bb[(nt*16+lq)*24 + quad*8] : zbuf;
    short8 bfr = *(const short8*)bp;
    f32x4 acc = {0.f,0.f,0.f,0.f};
    sc[nt] = __builtin_amdgcn_mfma_f32_16x16x32_bf16(afr, bfr, acc, 0, 0, 0);
  }

  // ---- head loop: 4 heads per group, barrier-free (strip-private) ----
  unsigned short* Pg = hgrp ? P1 : P0;
  f32x4 accv[4];
  for(int j=0;j<4;j++){
    int hh2 = hgrp*4 + j;
    const float* Alh = Al + hh2*128;
    float alr[4];
#pragma unroll
    for(int r=0;r<4;r++) alr[r] = Alh[strip + quad*4 + r];
#pragma unroll
    for(int nt=0;nt<8;nt++){
      int col = nt*16 + lq;
      float alc = Alh[col];
#pragma unroll
      for(int r=0;r<4;r++){
        int row = strip + quad*4 + r;
        float p = sc[nt][r] * __expf(alr[r] - alc);
        p = (col <= row) ? p : 0.f;
        Pg[row*168 + col] = bf16r(p);
      }
    }
    {
      int n = lane & 15, rg = lane >> 4;
#pragma unroll
      for(int rr=0;rr<4;rr++){
        int row = strip + rg*4 + rr;
        float ea = __expf(Alh[row]);
        Pg[row*168 + 128 + n] = bf16r(bf16f(Cb[row*24+n]) * ea);
      }
    }
    f32x4 acc2 = {0.f,0.f,0.f,0.f};
#pragma unroll
    for(int ks=0;ks<5;ks++){
      short8 bfr = *(const short8*)&XbT[(hh2*16+lq)*168 + ks*32 + quad*8];
      short8 af  = *(const short8*)&Pg[(strip+lq)*168 + ks*32 + quad*8];
      acc2 = __builtin_amdgcn_mfma_f32_16x16x32_bf16(af, bfr, acc2, 0, 0, 0);
    }
    const float* Dth = Dtl + hh2*128;
    float Dk = dskip[hh2];
#pragma unroll
    for(int r=0;r<4;r++){
      int l = strip + quad*4 + r;
      float xdt = bf16f(XbT[(hh2*16+lq)*168 + l]);
      float dtv = fmaxf(Dth[l], 1e-30f);
      acc2[r] += Dk * xdt * __frcp_rn(dtv);
    }
    accv[j] = acc2;
  }
  __syncthreads();   // (2) WAR: all reads of XbT/P done before overwrite

  // ---- stage z (XbT region), Wo/Wm (P0 region) ----
#pragma unroll
  for(int k=0;k<4;k++){
    int fi = tid + k*1024;
    int p = fi >> 5, s4 = fi & 31;
    uint2 zu = *(const uint2*)&zxz[(size_t)p*NT + t0 + s4*4];
    *(unsigned int*)&Zb[p*136 + s4*4]   = zu.x;
    *(unsigned int*)&Zb[p*136 + s4*4+2] = zu.y;
  }
#pragma unroll
  for(int k=0;k<2;k++){
    int fi = tid + k*1024;
    int n = fi >> 5, k4 = fi & 31;
    float4 wv = *(const float4*)&opw[(size_t)n*DIN + k4*4];
    *(unsigned int*)&Wo[n*136 + k4*4]   = pk_bf16(wv.x, wv.y);
    *(unsigned int*)&Wo[n*136 + k4*4+2] = pk_bf16(wv.z, wv.w);
  }
  {
    int fi = tid;                       // 0..1023
    int n = fi >> 4, k4 = fi & 15;
    float4 wv = *(const float4*)&mw[(size_t)n*HDIM + k4*4];
    *(unsigned int*)&Wm[n*72 + k4*4]   = pk_bf16(wv.x, wv.y);
    *(unsigned int*)&Wm[n*72 + k4*4+2] = pk_bf16(wv.z, wv.w);
  }
  __syncthreads();   // (3) Zb/Wo/Wm visible

  // ---- gate by silu(z), partial sum-of-squares, write Yn = y*nw (bf16) ----
  float part[4] = {0.f,0.f,0.f,0.f};
#pragma unroll
  for(int j=0;j<4;j++){
    int ch = (hgrp*4+j)*16 + lq;
    float nwv = nwl[ch];
#pragma unroll
    for(int r=0;r<4;r++){
      int l = strip + quad*4 + r;
      float zv = bf16f(Zb[ch*136 + l]);
      float g = zv * sigf(zv);
      float yv = accv[j][r] * g;
      part[r] += yv*yv;
      Yn[l*136 + ch] = bf16r(yv * nwv);
    }
  }
#pragma unroll
  for(int r=0;r<4;r++){
    part[r] += __shfl_xor(part[r],1); part[r] += __shfl_xor(part[r],2);
    part[r] += __shfl_xor(part[r],4); part[r] += __shfl_xor(part[r],8);
  }
  if(lq == 0){
#pragma unroll
    for(int r=0;r<4;r++) ssl[hgrp*128 + strip + quad*4 + r] = part[r];
  }
  __syncthreads();   // (4) Yn complete (both groups), ssl complete

  // ---- rms, out_proj (group computes 2 output nt), scale, softsign -> Tt ----
  float rms_[4];
#pragma unroll
  for(int r=0;r<4;r++){
    int l = strip + quad*4 + r;
    rms_[r] = rsqrtf((ssl[l] + ssl[128+l])*(1.0f/128.0f) + 1e-5f);
  }
  short8 afk[4];
#pragma unroll
  for(int ks=0;ks<4;ks++) afk[ks] = *(const short8*)&Yn[(strip+lq)*136 + ks*32 + quad*8];
  f32x4 aco[2];
#pragma unroll
  for(int ntl=0;ntl<2;ntl++){ aco[ntl] = (f32x4){0.f,0.f,0.f,0.f}; }
#pragma unroll
  for(int ntl=0;ntl<2;ntl++){
    int nt = hgrp*2 + ntl;
#pragma unroll
    for(int ks=0;ks<4;ks++){
      short8 bfr = *(const short8*)&Wo[(nt*16+lq)*136 + ks*32 + quad*8];
      aco[ntl] = __builtin_amdgcn_mfma_f32_16x16x32_bf16(afk[ks], bfr, aco[ntl], 0, 0, 0);
    }
  }
  __syncthreads();   // (5) all afk reads of Yn done before Tt overwrite
#pragma unroll
  for(int ntl=0;ntl<2;ntl++){
    int nt = hgrp*2 + ntl;
#pragma unroll
    for(int r=0;r<4;r++){
      int l = strip + quad*4 + r;
      float o = aco[ntl][r] * rms_[r];
      Tt[l*136 + nt*16+lq] = bf16r(o * rsqrtf(1.0f + o*o));
    }
  }
  __syncthreads();   // (6) Tt complete (both groups' cols)

  // ---- mlp: group computes 2 output nt ----
  f32x4 acm[2];
#pragma unroll
  for(int ntl=0;ntl<2;ntl++){ acm[ntl] = (f32x4){0.f,0.f,0.f,0.f}; }
#pragma unroll
  for(int ks=0;ks<2;ks++){
    short8 af = *(const short8*)&Tt[(strip+lq)*136 + ks*32 + quad*8];
#pragma unroll
    for(int ntl=0;ntl<2;ntl++){
      int nt = hgrp*2 + ntl;
      short8 bfr = *(const short8*)&Wm[(nt*16+lq)*72 + ks*32 + quad*8];
      acm[ntl] = __builtin_amdgcn_mfma_f32_16x16x32_bf16(af, bfr, acm[ntl], 0, 0, 0);
    }
  }
  // ---- residual / final output ----
  if(!last){
#pragma unroll
    for(int ntl=0;ntl<2;ntl++){
      int nt = hgrp*2 + ntl;
#pragma unroll
      for(int r=0;r<4;r++){
        int l = strip + quad*4 + r;
        int d = nt*16 + lq;
        size_t gi = (size_t)(t0+l)*HDIM + d;
        h[gi] += acm[ntl][r] + mbl[d];
      }
    }
  } else {
    float ps[4] = {0.f,0.f,0.f,0.f};
#pragma unroll
    for(int ntl=0;ntl<2;ntl++){
      int nt = hgrp*2 + ntl;
      int d = nt*16 + lq;
      float wo = wout[d];
      float bias = mbl[d];
#pragma unroll
      for(int r=0;r<4;r++){
        int l = strip + quad*4 + r;
        size_t gi = (size_t)(t0+l)*HDIM + d;
        float hn = h[gi] + acm[ntl][r] + bias;
        ps[r] += hn * wo;
      }
    }
#pragma unroll
    for(int r=0;r<4;r++){
      ps[r] += __shfl_xor(ps[r],1); ps[r] += __shfl_xor(ps[r],2);
      ps[r] += __shfl_xor(ps[r],4); ps[r] += __shfl_xor(ps[r],8);
    }
    if(hgrp == 1 && lq == 0){
#pragma unroll
      for(int r=0;r<4;r++) outb[strip + quad*4 + r] = ps[r];
    }
    __syncthreads();
    if(hgrp == 0 && lq == 0){
#pragma unroll
      for(int r=0;r<4;r++){
        int l = strip + quad*4 + r;
        out[t0 + l] = ps[r] + outb[l];
      }
    }
  }
}

extern "C" void kernel_launch(void* const* d_in, const int* in_sizes, int n_in,
                              void* d_out, int out_size, void* d_ws, size_t ws_size,
                              hipStream_t stream){
  const float* x          = (const float*)d_in[0];
  const float* w_in       = (const float*)d_in[1];
  const float* w_out      = (const float*)d_in[2];
  const float* in_proj_w  = (const float*)d_in[3];
  const float* conv_w     = (const float*)d_in[4];
  const float* conv_b     = (const float*)d_in[5];
  const float* dt_bias    = (const float*)d_in[6];
  const float* A_log      = (const float*)d_in[7];
  const float* D_skip     = (const float*)d_in[8];
  const float* init_st    = (const float*)d_in[9];
  const float* norm_w     = (const float*)d_in[10];
  const float* out_proj_w = (const float*)d_in[11];
  const float* mlp_w      = (const float*)d_in[12];
  const float* mlp_b      = (const float*)d_in[13];
  float* out = (float*)d_out;

  float* ws = (float*)d_ws;
  float* h    = ws; ws += (size_t)NT*HDIM;
  unsigned short* zxz = (unsigned short*)ws; ws += (size_t)(128*NT)/2;   // bf16 z
  float* zxc  = ws; ws += (size_t)168*NT;                                // fp32 conv-in + raw dt
  unsigned short* xbc = (unsigned short*)ws; ws += (size_t)(CDIM*NT)/2;  // bf16 conv out
  float* dt   = ws; ws += (size_t)NH*NT;
  float* acs  = ws; ws += (size_t)NH*NT;
  float* asum = ws; ws += (size_t)NB*NC*NH;
  float* S    = ws; ws += (size_t)NB*NC*NH*256;
  float* prev = ws; ws += (size_t)NB*NC*NH*256;
  unsigned short* whi = (unsigned short*)ws; ws += (size_t)(NBLK*EPROJ*HDIM)/2;
  unsigned short* wlo = (unsigned short*)ws; ws += (size_t)(NBLK*EPROJ*HDIM)/2;

  k_init_h<<<(NT*HDIM)/256, 256, 0, stream>>>(x, w_in, h);
  k_wsplit<<<(NBLK*EPROJ*HDIM + 255)/256, 256, 0, stream>>>(in_proj_w, whi, wlo);
  for(int i=0;i<NBLK;i++){
    k_inproj<<<NT/64, 256, 0, stream>>>(h, whi + (size_t)i*EPROJ*HDIM,
                                        wlo + (size_t)i*EPROJ*HDIM, zxz, zxc);
    k_mid   <<<NB*NC, 512, 0, stream>>>(zxc, conv_w + i*CDIM*KCONV, conv_b + i*CDIM,
                                        dt_bias + i*NH, A_log + i*NH,
                                        xbc, dt, acs, asum, S);
    k_scan  <<<NB*NH*4, 64, 0, stream>>>(S, asum, init_st + i*NH*256, prev);
    k_tail  <<<NB*NC, 1024, 0, stream>>>(xbc, zxz, dt, acs, prev, D_skip + i*NH,
                                         norm_w + i*DIN, out_proj_w + i*HDIM*DIN,
                                         mlp_w + i*HDIM*HDIM, mlp_b + i*HDIM, h,
                                         (i == NBLK-1) ? 1 : 0, w_out, out);
  }
}